// Round 8
// baseline (945.762 us; speedup 1.0000x reference)
//
#include <hip/hip_runtime.h>
#include <cstdint>
#include <cstddef>

// ---------------------------------------------------------------------------
// PatchModule R14.
// FAST PATH R14: conv_mfma = R9 structure + counted-vmcnt pipeline (T4),
//   with BOTH R10 failure causes removed:
//   (a) scale/shift preloaded to LDS before the K-loop -> in-loop VMEM ops
//       are EXCLUSIVELY the 4 GLL16s per STAGE -> vmcnt(4) arithmetic exact
//       (R10's absmax 0.817 came from hoisted epilogue scale/shift loads
//       inflating the outstanding-VMEM count).
//   (b) NO sched_barrier(0) pins (R10's 143us perf regression, m141-class):
//       the "memory" clobber on the waitcnt asm orders memory ops; MFMA
//       order follows data deps; frag reads are compiler IR loads (rule #18
//       does not apply). Reads drain pre-barrier via MFMA data deps.
//   Data and MFMA accumulation order bit-identical to R13.
// EXACT PATH: unchanged from R13 (proven 845us: full-K 64x64 fused blocks,
//   dbuf staging, XCD-chunked oc-adjacent grid, stride-72 transpose).
// All gathered indices masked &31 (rocprof replay poison safety).
// ---------------------------------------------------------------------------

typedef _Float16 f16;
typedef _Float16 f16x4 __attribute__((ext_vector_type(4)));
typedef _Float16 f16x8 __attribute__((ext_vector_type(8)));
typedef float    f32x4 __attribute__((ext_vector_type(4)));

constexpr int C_CH = 256;
constexpr int KTOT = 2304;
constexpr int PAT_POS = 3584;              // 2048+1024+512
constexpr int PAT_N   = PAT_POS * C_CH;

// async global->LDS, 16B per lane, dest = wave-uniform base + lane*16
#define GLL16(g, l) __builtin_amdgcn_global_load_lds(                        \
    (const __attribute__((address_space(1))) unsigned int*)(g),              \
    (__attribute__((address_space(3))) unsigned int*)(l), 16, 0, 0)

// ====== prep: weights fp32 [oc][ic*9+tap] -> f16 hi/lo [oc][tap*256+ic] ====
__global__ __launch_bounds__(256)
void prep_weights_kernel(const float* __restrict__ sw, const float* __restrict__ ew,
                         f16* __restrict__ wTs, f16* __restrict__ wTe,
                         f16* __restrict__ wTsL, f16* __restrict__ wTeL, int n)
{
    int i = blockIdx.x * 256 + threadIdx.x;
    if (i >= n) return;
    const int oc = i / KTOT;
    const int kp = i - oc * KTOT;
    const int tap = kp >> 8;
    const int ic  = kp & 255;
    const int src = oc * KTOT + ic * 9 + tap;
    const float vs = sw[src];
    const f16 hs = (f16)vs;
    wTs[i]  = hs;
    wTsL[i] = (f16)((vs - (float)hs) * 1024.f);
    const float ve = ew[src];
    const f16 he = (f16)ve;
    wTe[i]  = he;
    wTeL[i] = (f16)((ve - (float)he) * 1024.f);
}

// ================= prep: BN scale/shift per tower(2) x level(3) x oc(256) ==
__global__ __launch_bounds__(256)
void prep_bn_kernel(const float* sg, const float* sbb, const float* smm,
                    const float* svv, const float* sb,
                    const float* eg, const float* ebb, const float* emm,
                    const float* evv, const float* eb,
                    float* __restrict__ scale, float* __restrict__ shift)
{
    int i = blockIdx.x * 256 + threadIdx.x;
    if (i >= 1536) return;
    const int tw = i / 768;
    const int r  = i - tw * 768;          // lvl*256 + oc
    const int oc = r & 255;
    float g, bbv, m, v, cb;
    if (tw == 0) { g = sg[r]; bbv = sbb[r]; m = smm[r]; v = svv[r]; cb = sb[oc]; }
    else         { g = eg[r]; bbv = ebb[r]; m = emm[r]; v = evv[r]; cb = eb[oc]; }
    const float inv = 1.0f / sqrtf(v + 1e-5f);
    const float sc = g * inv;
    scale[i] = sc;
    shift[i] = (cb - m) * sc + bbv;
}

// ===================== zero-fill a f16 buffer (x8 groups) ==================
__global__ __launch_bounds__(256)
void zero16_kernel(f16x8* __restrict__ p, int n8)
{
    const int i = blockIdx.x * 256 + threadIdx.x;
    if (i < n8) p[i] = (f16x8){};
}

// ===== fill fpad16 hi/lo: padded-corner HWC f16 [lvlb][36*36][256] =========
__global__ __launch_bounds__(256)
void fpad16_fill_kernel(const float* __restrict__ feat0,
                        const float* __restrict__ feat1,
                        const float* __restrict__ feat2,
                        f16* __restrict__ xH, f16* __restrict__ xL)
{
    const int h    = blockIdx.x;
    const int lvlb = blockIdx.y;
    const int lvl  = lvlb >> 2, b = lvlb & 3;
    const int logW = 7 - lvl, H = 128 >> lvl;
    if (h >= H) return;                    // lvl2: rows h>=32 stay zero
    const int Wv = (H >= 34) ? 34 : 32;    // valid w count
    const int tid = threadIdx.x;
    const float* f = (lvl == 0) ? feat0 : (lvl == 1 ? feat1 : feat2);

    __shared__ float T[34][257];

    const int wl = tid & 31;
    const int cg = tid >> 5;               // 0..7
#pragma unroll
    for (int cb = 0; cb < 32; cb++) {
        const int c = cb * 8 + cg;
        const float* row = f + (((size_t)(b * C_CH + c)) << (2 * logW))
                             + ((size_t)h << logW);
        T[wl][c] = row[wl];
        if (wl < 2 && (wl + 32) < Wv) T[wl + 32][c] = row[wl + 32];
    }
    __syncthreads();
    const size_t rb = ((size_t)lvlb * 1296 + (size_t)(h + 2) * 36 + 2) * 256 + tid;
    for (int w = 0; w < Wv; w++) {
        const float v = T[w][tid];
        const f16 hh = (f16)v;
        xH[rb + (size_t)w * 256] = hh;
        xL[rb + (size_t)w * 256] = (f16)((v - (float)hh) * 1024.f);
    }
}

// ===== transpose-pad: feat fp32 [4][256][H][W] -> f16 HWC padded interior ==
__global__ __launch_bounds__(256)
void pad_hwc_kernel(const float* __restrict__ feat, f16* __restrict__ xT,
                    int H, int logW)
{
    const int W = 1 << logW;
    const int HW = H << logW;
    const int WP = W + 2, HP = H + 2;
    const int tid = threadIdx.x;
    const int nt  = HW >> 6;
    const int b   = blockIdx.x / nt;
    const int p0  = (blockIdx.x - b * nt) * 64;

    __shared__ f16 T[64][264];

    const int cBase = tid >> 4;
    const int pl4   = (tid & 15) * 4;
#pragma unroll
    for (int it = 0; it < 16; it++) {
        const int c = it * 16 + cBase;
        const float4 v = *(const float4*)(feat + (size_t)(b * C_CH + c) * HW + p0 + pl4);
        T[pl4 + 0][c] = (f16)v.x;
        T[pl4 + 1][c] = (f16)v.y;
        T[pl4 + 2][c] = (f16)v.z;
        T[pl4 + 3][c] = (f16)v.w;
    }
    __syncthreads();
    const int pl = tid >> 2;
    const int c0 = (tid & 3) * 64;
    const int p  = p0 + pl;
    const int h  = p >> logW, w = p & (W - 1);
    f16* dst = xT + ((size_t)(b * HP + h + 1) * WP + (w + 1)) * C_CH + c0;
#pragma unroll
    for (int i = 0; i < 64; i += 8)
        *(f16x8*)(dst + i) = *(const f16x8*)&T[pl][c0 + i];
}

// ============== zero border positions of a padded HWC f16 buffer ===========
__global__ __launch_bounds__(256)
void zero_cl_border_kernel(f16* __restrict__ xT, int H, int W, int n)
{
    const int WP = W + 2, HP = H + 2;
    const int BS = 2 * WP + 2 * H;
    int i = blockIdx.x * 256 + threadIdx.x;
    if (i >= n) return;
    const int ch = (i & 7) * 32;
    const int bc = i >> 3;
    const int b  = bc / BS;
    const int e  = bc - b * BS;
    int padpos;
    if (e < WP)            padpos = e;
    else if (e < 2 * WP)   padpos = (H + 1) * WP + (e - WP);
    else {
        const int e2 = e - 2 * WP;
        padpos = ((e2 >> 1) + 1) * WP + ((e2 & 1) ? (W + 1) : 0);
    }
    f16* dst = xT + ((size_t)b * HP * WP + padpos) * C_CH + ch;
    const f16x8 z = {};
#pragma unroll
    for (int j = 0; j < 32; j += 8) *(f16x8*)(dst + j) = z;
}

// =================== MFMA f16 conv3x3 + BN + ReLU (fast path) ==============
// R14: R9 staging/swizzle + counted-vmcnt pipeline. In-loop VMEM = GLL only
// (scale/shift pre-staged to LDS). No sched_barrier pins.
__global__ __launch_bounds__(256, 3)
void conv_mfma_kernel(const f16* __restrict__ xT, const f16* __restrict__ wT,
                      const float* __restrict__ scale,
                      const float* __restrict__ shift,
                      f16* __restrict__ y, int H, int logW, int opad)
{
    const int W  = 1 << logW;
    const int WP = W + 2, HP = H + 2;
    const int HW = H << logW;
    const int tid  = threadIdx.x;
    const int wv   = tid >> 6, lane = tid & 63;

    // --- XCD-chunked bijective swizzle (nwg % 8 == 0 for all levels) ---
    const int nwg = gridDim.x;
    const int bid = blockIdx.x;
    const int wg  = (bid & 7) * (nwg >> 3) + (bid >> 3);
    const int ocBase = (wg & 1) * 128;     // oc-tiles of one pos-tile adjacent
    const int pBase  = (wg >> 1) * 128;
    const int b    = pBase / HW;
    const int rem0 = pBase - b * HW;

    // 2 x (A[128][32] + B[128][32]) f16 = 32 KB
    __shared__ f16 sbuf[16384];
    __shared__ float scSh[256];            // [0:128)=scale, [128:256)=shift

    f32x4 acc[4][4];
#pragma unroll
    for (int i = 0; i < 4; i++)
#pragma unroll
        for (int j = 0; j < 4; j++) acc[i][j] = (f32x4){0.f, 0.f, 0.f, 0.f};

    // --- staging: per wave, 2 calls A + 2 calls B, 1KB each (lane*16B) ---
    const int lr = lane >> 2, ls = lane & 3;
    const int r0 = (wv * 2) * 16 + lr;
    const int r1 = (wv * 2 + 1) * 16 + lr;
    const int c0s = (ls ^ ((r0 >> 1) & 3)) * 8;
    const int c1s = (ls ^ ((r1 >> 1) & 3)) * 8;
    const f16* aSrc0 = wT + (size_t)(ocBase + r0) * KTOT + c0s;
    const f16* aSrc1 = wT + (size_t)(ocBase + r1) * KTOT + c1s;
    const int pp0 = rem0 + r0, pp1 = rem0 + r1;
    const f16* bSrc0 = xT + ((size_t)(b * HP + (pp0 >> logW) + 1) * WP
                             + (pp0 & (W - 1)) + 1) * C_CH + c0s;
    const f16* bSrc1 = xT + ((size_t)(b * HP + (pp1 >> logW) + 1) * WP
                             + (pp1 & (W - 1)) + 1) * C_CH + c1s;

    // --- fragment ds_read offsets (f16 units), swizzled cols ---
    const int rw = (wv & 1) * 64;
    const int cw = (wv >> 1) * 64;
    const int lm = lane & 15, lq = lane >> 4;
    int aOff[4], bOff[4];
#pragma unroll
    for (int mi = 0; mi < 4; mi++) {
        const int R = rw + mi * 16 + lm;
        aOff[mi] = R * 32 + ((lq ^ ((R >> 1) & 3)) << 3);
    }
#pragma unroll
    for (int ni = 0; ni < 4; ni++) {
        const int R = cw + ni * 16 + lm;
        bOff[ni] = 4096 + R * 32 + ((lq ^ ((R >> 1) & 3)) << 3);
    }

    auto STAGE = [&](int kn, int nb) {
        const int tap = kn >> 8;
        const int kh  = tap / 3;
        const int kw  = tap - 3 * kh;
        const int tOff = ((kh - 1) * WP + (kw - 1)) * C_CH + (kn & 255);
        f16* lb = &sbuf[nb * 8192 + wv * 1024];          // wave-uniform base
        GLL16(aSrc0 + kn, lb);
        GLL16(aSrc1 + kn, lb + 512);
        GLL16(bSrc0 + tOff, lb + 4096);
        GLL16(bSrc1 + tOff, lb + 4096 + 512);
    };

    // preload BN params to LDS BEFORE the loop so the K-loop contains no
    // VMEM ops other than the GLLs (exact vmcnt accounting).
    if (tid < 128) {
        scSh[tid]       = scale[ocBase + tid];
        scSh[128 + tid] = shift[ocBase + tid];
    }
    STAGE(0, 0);
    __syncthreads();                       // drains vmcnt(0)+lgkm: tile0+BN in
    constexpr int NT = KTOT / 32;          // 72 K-steps
    for (int t = 0; t < NT; t++) {
        if (t + 1 < NT) {
            STAGE(t + 1, (t + 1) & 1);     // issue-first; flies across barrier
            asm volatile("s_waitcnt vmcnt(4)" ::: "memory");  // t landed
        } else {
            asm volatile("s_waitcnt vmcnt(0)" ::: "memory");  // tail drain
        }
        __builtin_amdgcn_s_barrier();      // all waves' tile-t loads landed
        const f16* sb = &sbuf[(t & 1) * 8192];
        f16x8 af[4], bf[4];
#pragma unroll
        for (int mi = 0; mi < 4; mi++) af[mi] = *(const f16x8*)(sb + aOff[mi]);
#pragma unroll
        for (int ni = 0; ni < 4; ni++) bf[ni] = *(const f16x8*)(sb + bOff[ni]);
#pragma unroll
        for (int mi = 0; mi < 4; mi++)
#pragma unroll
            for (int ni = 0; ni < 4; ni++)
                acc[mi][ni] = __builtin_amdgcn_mfma_f32_16x16x32_f16(
                    af[mi], bf[ni], acc[mi][ni], 0, 0, 0);
        __builtin_amdgcn_s_barrier();      // reads of buf[t&1] done (MFMA
                                           // deps drained lgkm) before t+2
    }

    float sc[4][4], sh[4][4];
#pragma unroll
    for (int mi = 0; mi < 4; mi++)
#pragma unroll
        for (int r = 0; r < 4; r++) {
            const int chl = rw + mi * 16 + lq * 4 + r;
            sc[mi][r] = scSh[chl];
            sh[mi][r] = scSh[128 + chl];
        }
#pragma unroll
    for (int ni = 0; ni < 4; ni++) {
        const int pp = rem0 + cw + ni * 16 + lm;
        size_t dst;
        if (opad) {
            const int h2 = pp >> logW, w2 = pp & (W - 1);
            dst = ((size_t)(b * HP + h2 + 1) * WP + (w2 + 1)) * C_CH;
        } else {
            dst = (size_t)(pBase + cw + ni * 16 + lm) * C_CH;
        }
#pragma unroll
        for (int mi = 0; mi < 4; mi++) {
            const int ocb = ocBase + rw + mi * 16 + lq * 4;
            f16x4 o;
#pragma unroll
            for (int r = 0; r < 4; r++)
                o[r] = (f16)fmaxf(fmaf(acc[mi][ni][r], sc[mi][r], sh[mi][r]), 0.f);
            *(f16x4*)(y + dst + ocb) = o;
        }
    }
}

// ============ ehead 1x1 + sigmoid from dense HWC f16 ex -> em map ==========
__global__ __launch_bounds__(256)
void ehead_em_f16_kernel(const f16* __restrict__ ex, const float* __restrict__ ehw,
                         const float* __restrict__ ehb, float* __restrict__ em)
{
    const int wv   = threadIdx.x >> 6;
    const int lane = threadIdx.x & 63;
    const int posBase = (blockIdx.x * 4 + wv) * 8;
    const int sp = lane >> 3;
    const int t  = lane & 7;
    const int cg = t * 32;
    const f16* base = ex + (size_t)(posBase + sp) * C_CH + cg;
    float s = 0.f;
#pragma unroll
    for (int i = 0; i < 32; i += 8) {
        const f16x8 v = *(const f16x8*)(base + i);
#pragma unroll
        for (int j = 0; j < 8; j++)
            s = fmaf((float)v[j], ehw[cg + i + j], s);
    }
    s += __shfl_xor(s, 1);
    s += __shfl_xor(s, 2);
    s += __shfl_xor(s, 4);
    if (t == 0) em[posBase + sp] = 1.0f / (1.0f + expf(-(s + ehb[0])));
}

// ====== EXACT paired-f16 MFMA, FULL-K, 64oc x 64pos, fused epilogues =======
// 1D grid, XCD-chunked; wgs&3 = oc quarter (adjacent -> B L2 reuse x4).
// share: 912 blocks (12 lvlb x 19 pos tiles x 4 ocq).
// ent:   768 blocks (12 lvlb x 16 cell tiles x 4 ocq).
// Double-buffered staging (conv-R9-proven schedule).
template<bool IS_SHARE>
__global__ __launch_bounds__(256, 2)
void exact_full_kernel(const f16* __restrict__ xHg, const f16* __restrict__ xLg,
                       const f16* __restrict__ wH, const f16* __restrict__ wL,
                       const float* __restrict__ scale,
                       const float* __restrict__ shift,
                       float* __restrict__ xsp,
                       f16* __restrict__ xOH, f16* __restrict__ xOL,
                       float* __restrict__ apePart, const float* __restrict__ ehw)
{
    constexpr int NTL    = IS_SHARE ? 19 : 16;
    constexpr int IPITCH = IS_SHARE ? 36 : 34;
    constexpr int IPLANE = IS_SHARE ? 1296 : 1156;

    const int tid  = threadIdx.x;
    const int wv   = tid >> 6, lane = tid & 63;

    // --- XCD-chunked bijective swizzle; oc-quarters adjacent ---
    const int nwg = gridDim.x;             // 912 or 768, % 8 == 0
    const int bid = blockIdx.x;
    const int wgs = (bid & 7) * (nwg >> 3) + (bid >> 3);
    const int ocq = wgs & 3;
    const int ti  = wgs >> 2;
    const int lvlb = ti / NTL;
    const int tile = ti - lvlb * NTL;
    const int posBase = tile * 64;
    const int ocBase  = ocq * 64;
    const int lvl  = lvlb >> 2;

    // 2 x (AsH|AsL|BsH|BsL each [64][32]) = 32 KB; epilogue reuses region
    __shared__ f16 sbuf[16384];

    f32x4 accH[2][2], accX[2][2];
#pragma unroll
    for (int i = 0; i < 2; i++)
#pragma unroll
        for (int j = 0; j < 2; j++) {
            accH[i][j] = (f32x4){0.f, 0.f, 0.f, 0.f};
            accX[i][j] = (f32x4){0.f, 0.f, 0.f, 0.f};
        }

    // --- staging: per wave 4 GLL16 (A-H, A-L, B-H, B-L), rows wv*16..+15 ---
    const int lr = lane >> 2, ls = lane & 3;
    const int rA = wv * 16 + lr;                   // 0..63
    const int cAs = (ls ^ ((rA >> 1) & 3)) * 8;    // pre-swizzled col
    const f16* aSrcH = wH + (size_t)(ocBase + rA) * KTOT + cAs;
    const f16* aSrcL = wL + (size_t)(ocBase + rA) * KTOT + cAs;

    int n = posBase + rA;
    if (IS_SHARE && n > 1155) n = 1155;            // tail tile clamp (masked)
    int po;
    if (IS_SHARE) { const int ph = n / 34; po = ph * 36 + (n - ph * 34); }
    else          { po = (n >> 5) * 34 + (n & 31); }
    const f16* bSrcH = xHg + ((size_t)lvlb * IPLANE + po) * 256 + cAs;
    const f16* bSrcL = xLg + ((size_t)lvlb * IPLANE + po) * 256 + cAs;

    // --- fragment ds_read offsets (f16 units), swizzled cols ---
    const int rw = (wv & 1) * 32;                  // oc within 64
    const int cw = (wv >> 1) * 32;                 // pos within 64
    const int lm = lane & 15, lq = lane >> 4;
    int aOff[2], bOff[2];
#pragma unroll
    for (int mi = 0; mi < 2; mi++) {
        const int R = rw + mi * 16 + lm;
        aOff[mi] = R * 32 + ((lq ^ ((R >> 1) & 3)) << 3);
    }
#pragma unroll
    for (int ni = 0; ni < 2; ni++) {
        const int R = cw + ni * 16 + lm;
        bOff[ni] = R * 32 + ((lq ^ ((R >> 1) & 3)) << 3);
    }

    auto STAGE = [&](int kn, int nb) {
        const int tap = kn >> 8;
        const int th  = tap / 3;
        const int tOff = (th * IPITCH + (tap - 3 * th)) * 256 + (kn & 255);
        f16* lb = &sbuf[nb * 8192 + wv * 512];     // wave-uniform bases
        GLL16(aSrcH + kn, lb);
        GLL16(aSrcL + kn, lb + 2048);
        GLL16(bSrcH + tOff, lb + 4096);
        GLL16(bSrcL + tOff, lb + 6144);
    };

    STAGE(0, 0);
    __syncthreads();                       // drains vmcnt(0): tile 0 landed
    int cur = 0;
    for (int ko = 0; ko < KTOT; ko += 32) {
        if (ko + 32 < KTOT) STAGE(ko + 32, cur ^ 1);   // overlap with compute
        const f16* sb = &sbuf[cur * 8192];
        f16x8 aH[2], aL[2];
#pragma unroll
        for (int mi = 0; mi < 2; mi++) {
            aH[mi] = *(const f16x8*)(sb + aOff[mi]);
            aL[mi] = *(const f16x8*)(sb + 2048 + aOff[mi]);
        }
#pragma unroll
        for (int ni = 0; ni < 2; ni++) {
            const f16x8 bh = *(const f16x8*)(sb + 4096 + bOff[ni]);
            const f16x8 bl = *(const f16x8*)(sb + 6144 + bOff[ni]);
#pragma unroll
            for (int mi = 0; mi < 2; mi++)
                accH[mi][ni] = __builtin_amdgcn_mfma_f32_16x16x32_f16(
                    aH[mi], bh, accH[mi][ni], 0, 0, 0);
#pragma unroll
            for (int mi = 0; mi < 2; mi++)
                accX[mi][ni] = __builtin_amdgcn_mfma_f32_16x16x32_f16(
                    aH[mi], bl, accX[mi][ni], 0, 0, 0);
#pragma unroll
            for (int mi = 0; mi < 2; mi++)
                accX[mi][ni] = __builtin_amdgcn_mfma_f32_16x16x32_f16(
                    aL[mi], bh, accX[mi][ni], 0, 0, 0);
        }
        __syncthreads();                   // drain next-tile loads + flip
        cur ^= 1;
    }

    if constexpr (IS_SHARE) {
        // BN+ReLU+mask; write xsp fp32 CHW; stage hi/lo into LDS transpose
        // buf with stride 72 f16 (144B rows: 16B-aligned, 2-way banks).
#pragma unroll
        for (int mi = 0; mi < 2; mi++)
#pragma unroll
            for (int r = 0; r < 4; r++) {
                const int chl = rw + mi * 16 + lq * 4 + r;    // 0..63
                const int oc  = ocBase + chl;
                const float sc = scale[lvl * 256 + oc];
                const float sh = shift[lvl * 256 + oc];
#pragma unroll
                for (int ni = 0; ni < 2; ni++) {
                    const int pl  = cw + ni * 16 + lm;        // 0..63
                    const int nn  = posBase + pl;
                    const float val = accH[mi][ni][r]
                                    + accX[mi][ni][r] * (1.0f / 1024.0f);
                    const int ph = nn / 34;
                    const int pw = nn - ph * 34;
                    const bool valid = (nn < 1156) && (ph >= 1) && (pw >= 1) &&
                                       (lvl < 2 || (ph <= 32 && pw <= 32));
                    const float o = valid ? fmaxf(fmaf(val, sc, sh), 0.f) : 0.f;
                    if (nn < 1156)
                        xsp[((size_t)(lvlb * 256 + oc)) * 1156 + nn] = o;
                    const f16 h = (f16)o;
                    sbuf[pl * 72 + chl]        = h;
                    sbuf[4608 + pl * 72 + chl] = (f16)((o - (float)h) * 1024.f);
                }
            }
        __syncthreads();
        const int p  = tid >> 2;
        const int cg = (tid & 3) * 16;
        const int n2 = posBase + p;
        if (n2 < 1156) {
            const size_t gb = ((size_t)lvlb * 1156 + n2) * 256 + ocBase + cg;
            *(f16x8*)(xOH + gb)     = *(const f16x8*)(sbuf + p * 72 + cg);
            *(f16x8*)(xOH + gb + 8) = *(const f16x8*)(sbuf + p * 72 + cg + 8);
            *(f16x8*)(xOL + gb)     = *(const f16x8*)(sbuf + 4608 + p * 72 + cg);
            *(f16x8*)(xOL + gb + 8) = *(const f16x8*)(sbuf + 4608 + p * 72 + cg + 8);
        }
    } else {
        // BN+ReLU; ehead contraction over this block's 64-oc slice
        float* pa = (float*)sbuf;          // [64 cells][8 contributors]
        float pni[2] = {0.f, 0.f};
#pragma unroll
        for (int mi = 0; mi < 2; mi++)
#pragma unroll
            for (int r = 0; r < 4; r++) {
                const int oc = ocBase + rw + mi * 16 + lq * 4 + r;
                const float sc = scale[768 + lvl * 256 + oc];
                const float sh = shift[768 + lvl * 256 + oc];
                const float w  = ehw[oc];
#pragma unroll
                for (int ni = 0; ni < 2; ni++) {
                    const float val = accH[mi][ni][r]
                                    + accX[mi][ni][r] * (1.0f / 1024.0f);
                    pni[ni] = fmaf(w, fmaxf(fmaf(val, sc, sh), 0.f), pni[ni]);
                }
            }
        const int slot = lq + 4 * (wv & 1);
#pragma unroll
        for (int ni = 0; ni < 2; ni++)
            pa[(cw + ni * 16 + lm) * 8 + slot] = pni[ni];
        __syncthreads();
        if (tid < 64) {
            float s = pa[tid * 8];
#pragma unroll
            for (int j = 1; j < 8; j++) s += pa[tid * 8 + j];
            apePart[(size_t)ocq * 12288 + lvlb * 1024 + posBase + tid] = s;
        }
    }
}

// ======= ape finalize: sum 4 oc-quarter partials + bias + sigmoid ==========
__global__ __launch_bounds__(256)
void ape_fin_kernel(const float* __restrict__ apePart,
                    const float* __restrict__ ehb, float* __restrict__ ape)
{
    const int i = blockIdx.x * 256 + threadIdx.x;
    if (i >= 12288) return;
    float s = apePart[i];
    s += apePart[12288 + i];
    s += apePart[24576 + i];
    s += apePart[36864 + i];
    ape[i] = 1.0f / (1.0f + expf(-(s + ehb[0])));
}

// ===================== top-k, all levels (grid 12) =========================
__global__ __launch_bounds__(1024)
void topk_all_kernel(const float* __restrict__ ape, const int* __restrict__ coords,
                     int* __restrict__ xy_int, float* __restrict__ out,
                     int xo0, int xo1, int xo2)
{
    const int lvl = blockIdx.x >> 2;
    const int b   = blockIdx.x & 3;
    const int nk  = 512 >> lvl;
    const int tid = threadIdx.x;
    __shared__ unsigned long long keys[1024];

    const int rr = coords[tid] & 31;
    const int cc0 = coords[1024 + tid] & 31;
    const float v = ape[lvl * 4096 + (b << 10) + (rr << 5) + cc0];
    unsigned u = __float_as_uint(v);
    unsigned mono = (u & 0x80000000u) ? ~u : (u | 0x80000000u);
    keys[tid] = (((unsigned long long)(~mono)) << 32) | (unsigned)tid;
    __syncthreads();

    for (int k = 2; k <= 1024; k <<= 1) {
        for (int j = k >> 1; j > 0; j >>= 1) {
            const int ixj = tid ^ j;
            if (ixj > tid) {
                const bool up = ((tid & k) == 0);
                const unsigned long long a = keys[tid], c = keys[ixj];
                if ((a > c) == up) { keys[tid] = c; keys[ixj] = a; }
            }
            __syncthreads();
        }
    }

    if (tid < nk) {
        const int i  = (int)(keys[tid] & 0x3FFu);
        const int r  = coords[i] & 31;
        const int c  = coords[1024 + i] & 31;
        const int intOff = 8192 - (8192 >> lvl);
        const int o  = intOff + (b * nk + tid) * 2;
        xy_int[o]     = r;
        xy_int[o + 1] = c;
        const int xo = (lvl == 0) ? xo0 : (lvl == 1 ? xo1 : xo2);
        out[xo + (b * nk + tid) * 2]     = (float)r;
        out[xo + (b * nk + tid) * 2 + 1] = (float)c;
    }
}

// ====== EXACT fp32 pat conv at top-k, all levels, split-K x4 ===============
__global__ __launch_bounds__(256, 2)
void sparse_pat_all_kernel(const float* __restrict__ xsp_base,
                           const float* __restrict__ wgt,
                           const int* __restrict__ xy_int,
                           float* __restrict__ part)
{
    const int x = blockIdx.x;
    const int lvl  = (x < 32) ? 0 : (x < 48 ? 1 : 2);
    const int xloc = x - ((lvl == 0) ? 0 : (lvl == 1 ? 32 : 48));
    const int lognk = 9 - lvl;
    const int pBase = xloc * 64;
    const int b = pBase >> lognk;
    const int intOff   = 8192 - (8192 >> lvl);
    const int posStart = 4096 - (4096 >> lvl);
    const float* xb = xsp_base + ((size_t)(lvl * 4 + b) * C_CH) * 1156;

    const int tid = threadIdx.x;
    const int ocBase = blockIdx.y * 64;
    const int kStart = blockIdx.z * 576;
    const int kEnd   = kStart + 576;

    __shared__ float As[8][68];
    __shared__ float Bs[8][68];
    __shared__ int pofs[64];

    if (tid < 64) {
        const int r = xy_int[intOff + (pBase + tid) * 2]     & 31;
        const int c = xy_int[intOff + (pBase + tid) * 2 + 1] & 31;
        pofs[tid] = (r + 1) * 34 + (c + 1);
    }
    __syncthreads();

    float acc[4][4] = {};
    const int tm = tid >> 4, tn = tid & 15;
    const int aRow = tid & 63, aK = (tid >> 6) * 2;
    const float* aPtr = wgt + (size_t)(ocBase + aRow) * KTOT + aK;
    const int bK  = tid >> 5;
    const int bN2 = (tid & 31) * 2;
    const int off0 = pofs[bN2], off1 = pofs[bN2 + 1];

    float2 av = *(const float2*)(aPtr + kStart);
    int ic = (kStart + bK) / 9;
    int r9 = (kStart + bK) - ic * 9;
    int kh = r9 / 3 - 1, kw = r9 - (r9 / 3) * 3 - 1;
    const float* bb0 = xb + (size_t)ic * 1156 + kh * 34 + kw;
    float bv0 = bb0[off0], bv1 = bb0[off1];

    for (int k0 = kStart; k0 < kEnd; k0 += 8) {
        __syncthreads();
        As[aK][aRow] = av.x; As[aK + 1][aRow] = av.y;
        Bs[bK][bN2] = bv0;   Bs[bK][bN2 + 1] = bv1;
        __syncthreads();
        if (k0 + 8 < kEnd) {
            av = *(const float2*)(aPtr + k0 + 8);
            const int k = k0 + 8 + bK;
            ic = k / 9; r9 = k - ic * 9;
            kh = r9 / 3 - 1; kw = r9 - (r9 / 3) * 3 - 1;
            const float* bbn = xb + (size_t)ic * 1156 + kh * 34 + kw;
            bv0 = bbn[off0]; bv1 = bbn[off1];
        }
#pragma unroll
        for (int kk = 0; kk < 8; kk++) {
            float a0[4], b0[4];
            *(float4*)&a0[0] = *(const float4*)&As[kk][tm * 4];
            *(float4*)&b0[0] = *(const float4*)&Bs[kk][tn * 4];
#pragma unroll
            for (int i = 0; i < 4; i++)
#pragma unroll
                for (int j = 0; j < 4; j++)
                    acc[i][j] = fmaf(a0[i], b0[j], acc[i][j]);
        }
    }

    float* op = part + (size_t)blockIdx.z * PAT_N;
#pragma unroll
    for (int j = 0; j < 4; j++) {
        float4 o;
        o.x = acc[0][j]; o.y = acc[1][j]; o.z = acc[2][j]; o.w = acc[3][j];
        *(float4*)(op + (size_t)(posStart + pBase + tn * 4 + j) * C_CH
                      + ocBase + tm * 4) = o;
    }
}

// ===== pat split-K reduce (fixed order) + BN + ReLU -> af [3584][256] ======
__global__ __launch_bounds__(256)
void pat_reduce_kernel(const float* __restrict__ part,
                       const float* __restrict__ cb,
                       const float* __restrict__ bng, const float* __restrict__ bnb,
                       const float* __restrict__ bnm, const float* __restrict__ bnv,
                       float* __restrict__ af)
{
    const int i4 = (blockIdx.x * 256 + threadIdx.x) * 4;
    if (i4 >= PAT_N) return;
    const int pos = i4 >> 8;
    const int oc0 = i4 & 255;
    const int lvl = (pos < 2048) ? 0 : (pos < 3072 ? 1 : 2);
    float4 s = *(const float4*)(part + i4);
#pragma unroll
    for (int z = 1; z < 4; z++) {
        const float4 t = *(const float4*)(part + (size_t)z * PAT_N + i4);
        s.x += t.x; s.y += t.y; s.z += t.z; s.w += t.w;
    }
    const float4 g  = *(const float4*)(bng + lvl * 256 + oc0);
    const float4 bb = *(const float4*)(bnb + lvl * 256 + oc0);
    const float4 m  = *(const float4*)(bnm + lvl * 256 + oc0);
    const float4 v  = *(const float4*)(bnv + lvl * 256 + oc0);
    const float4 cb4 = *(const float4*)(cb + oc0);
    float4 o;
    {
        float inv = 1.0f / sqrtf(v.x + 1e-5f); float sc = g.x * inv;
        o.x = fmaxf(fmaf(s.x, sc, (cb4.x - m.x) * sc + bb.x), 0.f);
        inv = 1.0f / sqrtf(v.y + 1e-5f); sc = g.y * inv;
        o.y = fmaxf(fmaf(s.y, sc, (cb4.y - m.y) * sc + bb.y), 0.f);
        inv = 1.0f / sqrtf(v.z + 1e-5f); sc = g.z * inv;
        o.z = fmaxf(fmaf(s.z, sc, (cb4.z - m.z) * sc + bb.z), 0.f);
        inv = 1.0f / sqrtf(v.w + 1e-5f); sc = g.w * inv;
        o.w = fmaxf(fmaf(s.w, sc, (cb4.w - m.w) * sc + bb.w), 0.f);
    }
    *(float4*)(af + i4) = o;
}

// ============ head + final boxes, all levels (grid 3584) ===================
__global__ __launch_bounds__(256)
void head_final_all_kernel(const float* __restrict__ af, const float* __restrict__ hw,
                           const float* __restrict__ hb, const int* __restrict__ xy_int,
                           float* __restrict__ out, int fo0, int fo1, int fo2)
{
    const int pos = blockIdx.x;
    const int lvl = (pos < 2048) ? 0 : (pos < 3072 ? 1 : 2);
    const int local = pos - (4096 - (4096 >> lvl));
    const int intOff = 8192 - (8192 >> lvl);
    const int fo = (lvl == 0) ? fo0 : (lvl == 1 ? fo1 : fo2);
    const int tid  = threadIdx.x;
    const int j4   = tid >> 6;
    const int lane = tid & 63;
    const float* a = af + (size_t)pos * C_CH;
    const float* w = hw + j4 * C_CH;
    float sum = 0.f;
#pragma unroll
    for (int i = 0; i < 4; i++)
        sum = fmaf(a[lane + 64 * i], w[lane + 64 * i], sum);
#pragma unroll
    for (int off = 32; off > 0; off >>= 1) sum += __shfl_down(sum, off);
    if (lane == 0) {
        const float pc = 1.0f / (1.0f + expf(-(sum + hb[j4])));
        const float ax = (float)xy_int[intOff + local * 2];
        const float ay = (float)xy_int[intOff + local * 2 + 1];
        float val;
        if      (j4 == 0) val = ax - 16.0f * pc;
        else if (j4 == 1) val = ay - 16.0f * pc;
        else if (j4 == 2) val = ax + 16.0f * pc;
        else              val = ay + 16.0f * pc;
        out[fo + local * 4 + j4] = val;
    }
}

// ============================== launcher ===================================
extern "C" void kernel_launch(void* const* d_in, const int* in_sizes, int n_in,
                              void* d_out, int out_size, void* d_ws, size_t ws_size,
                              hipStream_t stream) {
    const float* feat[3] = {(const float*)d_in[0], (const float*)d_in[1],
                            (const float*)d_in[2]};
    const int*   coords  = (const int*)d_in[3];
    const float* sw  = (const float*)d_in[4];
    const float* sb  = (const float*)d_in[5];
    const float* sg  = (const float*)d_in[6];
    const float* sbb = (const float*)d_in[7];
    const float* smm = (const float*)d_in[8];
    const float* svv = (const float*)d_in[9];
    const float* ew  = (const float*)d_in[10];
    const float* eb  = (const float*)d_in[11];
    const float* eg  = (const float*)d_in[12];
    const float* ebb = (const float*)d_in[13];
    const float* emm = (const float*)d_in[14];
    const float* evv = (const float*)d_in[15];
    const float* pw  = (const float*)d_in[16];
    const float* pb  = (const float*)d_in[17];
    const float* pg  = (const float*)d_in[18];
    const float* pbb = (const float*)d_in[19];
    const float* pmm = (const float*)d_in[20];
    const float* pvv = (const float*)d_in[21];
    const float* ehw = (const float*)d_in[22];
    const float* ehb = (const float*)d_in[23];
    const float* hww = (const float*)d_in[24];
    const float* hbb = (const float*)d_in[25];

    float* out = (float*)d_out;
    char*  ws  = (char*)d_ws;

    // ---- workspace layout (bytes from ws) ----
    f16*   wTs    = (f16*)(ws);                         // 0        (1.18MB)
    f16*   wTe    = (f16*)(ws + 1310720);
    f16*   wTsL   = (f16*)(ws + 2621440);
    f16*   wTeL   = (f16*)(ws + 3932160);
    float* scales = (float*)(ws + 5242880);
    float* shifts = (float*)(ws + 5251072);
    // exact path
    f16*   fpadH  = (f16*)(ws + 6291456);               // 6MB   (7.96MB)
    f16*   fpadL  = (f16*)(ws + 14254080);              // contiguous after H
    float* patPart= (float*)(ws + 6291456);             // reuses fpad16 (dead)
    float* af     = (float*)(ws + 23068672);            // 22MB  (3.5MB)
    f16*   xspH   = (f16*)(ws + 90177536);              // 86MB  (6.8MB)
    f16*   xspL   = (f16*)(ws + 97280000);
    float* xsp    = (float*)(ws + 104857600);           // 100MB (13.6MB)
    float* ape    = (float*)(ws + 119537664);           // 114MB (48KB)
    int*   xy_int = (int*)  (ws + 119603200);           // (32KB)
    float* apePart= (float*)(ws + 119668736);           // (192KB)
    // fast path (runs after exact path; reuses dead exact regions)
    f16*   featT  = (f16*)(ws + 27262976);              // 26MB (34.6MB, lvl0)
    f16*   xsT    = (f16*)(ws + 65011712);              // 62MB (34.6MB) disjoint
    f16*   exT    = (f16*)(ws + 27262976);              // reuses featT (dead)

    const int Hs[3]    = {128, 64, 32};
    const int logWs[3] = {7, 6, 5};
    const int nks[3]   = {512, 256, 128};

    size_t off = 0;
    size_t emOff[3], finOff[3], xyOff[3];
    for (int l = 0; l < 3; l++) {
        const int HW = Hs[l] * Hs[l];
        emOff[l]  = off; off += (size_t)4 * HW;
        finOff[l] = off; off += (size_t)4 * nks[l] * 4;
        xyOff[l]  = off; off += (size_t)4 * nks[l] * 2;
    }

    // -------- prep --------
    prep_weights_kernel<<<(C_CH * KTOT + 255) / 256, 256, 0, stream>>>(
        sw, ew, wTs, wTe, wTsL, wTeL, C_CH * KTOT);
    prep_bn_kernel<<<6, 256, 0, stream>>>(sg, sbb, smm, svv, sb,
                                          eg, ebb, emm, evv, eb, scales, shifts);

    // -------- exact path --------
    zero16_kernel<<<(995328 + 255) / 256, 256, 0, stream>>>((f16x8*)fpadH, 995328);
    fpad16_fill_kernel<<<dim3(34, 12), 256, 0, stream>>>(
        feat[0], feat[1], feat[2], fpadH, fpadL);
    exact_full_kernel<true><<<912, 256, 0, stream>>>(
        fpadH, fpadL, wTs, wTsL, scales, shifts, xsp, xspH, xspL,
        nullptr, nullptr);
    exact_full_kernel<false><<<768, 256, 0, stream>>>(
        xspH, xspL, wTe, wTeL, scales, shifts, nullptr, nullptr, nullptr,
        apePart, ehw);
    ape_fin_kernel<<<48, 256, 0, stream>>>(apePart, ehb, ape);
    topk_all_kernel<<<12, 1024, 0, stream>>>(
        ape, coords, xy_int, out, (int)xyOff[0], (int)xyOff[1], (int)xyOff[2]);
    sparse_pat_all_kernel<<<dim3(56, 4, 4), 256, 0, stream>>>(
        xsp, pw, xy_int, patPart);
    pat_reduce_kernel<<<(PAT_N / 1024), 256, 0, stream>>>(
        patPart, pb, pg, pbb, pmm, pvv, af);
    head_final_all_kernel<<<PAT_POS, 256, 0, stream>>>(
        af, hww, hbb, xy_int, out, (int)finOff[0], (int)finOff[1], (int)finOff[2]);

    // -------- fast path (f16 MFMA), per level --------
    for (int lvl = 0; lvl < 3; lvl++) {
        const int H = Hs[lvl], logW = logWs[lvl];
        const int W = H;
        const int HW = H << logW;
        const int WP = W + 2;
        const int nbord = 4 * (2 * WP + 2 * H) * 8;

        pad_hwc_kernel<<<4 * HW / 64, 256, 0, stream>>>(feat[lvl], featT, H, logW);
        zero_cl_border_kernel<<<(nbord + 255) / 256, 256, 0, stream>>>(
            featT, H, W, nbord);
        zero_cl_border_kernel<<<(nbord + 255) / 256, 256, 0, stream>>>(
            xsT, H, W, nbord);
        dim3 gconv((4 * HW / 128) * 2);     // 1D: wg&1 = oc tile, wg>>1 = pos
        conv_mfma_kernel<<<gconv, 256, 0, stream>>>(
            featT, wTs, scales + lvl * 256, shifts + lvl * 256, xsT, H, logW, 1);
        conv_mfma_kernel<<<gconv, 256, 0, stream>>>(
            xsT, wTe, scales + 768 + lvl * 256, shifts + 768 + lvl * 256,
            exT, H, logW, 0);
        ehead_em_f16_kernel<<<4 * HW / 32, 256, 0, stream>>>(
            exT, ehw, ehb, out + emOff[lvl]);
    }
}

// Round 9
// 797.506 us; speedup vs baseline: 1.1859x; 1.1859x over previous
//
#include <hip/hip_runtime.h>
#include <cstdint>
#include <cstddef>

// ---------------------------------------------------------------------------
// PatchModule R15.
// FAST PATH: conv_mfma REVERTED to the R13-proven schedule (counted-vmcnt
//   abandoned permanently: R10 and R14 both raced -> absmax 0.817. Root
//   cause: raw s_barrier is not an IR-level memory fence, so frag ds_reads
//   can cross it; per-wave vmcnt only covers own loads, not other waves').
// EXACT PATH R15: sparse_pat fp32 VALU GEMM (~55us) -> pat_mfma using the
//   PROVEN exact_full template (paired-f16 MFMA, GLL16 + XOR slot-swizzle,
//   dbuf __syncthreads schedule), split-K x2, 32pos x 64oc tiles, 896
//   blocks. Inputs already in f16 hi/lo HWC (xspH/xspL); pofs = r*34+c
//   makes tap addressing identical to the ent variant. pat weights get
//   hi/lo split in prep_weights (wTp/wTpL, parked in exact-path-dead ws).
//   pat_reduce now sums 2 fixed-order partials (still deterministic).
//   Error class = share/ent conversion (~1e-6); box tolerance >=0.24.
// All gathered indices masked &31 (rocprof replay poison safety).
// ---------------------------------------------------------------------------

typedef _Float16 f16;
typedef _Float16 f16x4 __attribute__((ext_vector_type(4)));
typedef _Float16 f16x8 __attribute__((ext_vector_type(8)));
typedef float    f32x4 __attribute__((ext_vector_type(4)));

constexpr int C_CH = 256;
constexpr int KTOT = 2304;
constexpr int PAT_POS = 3584;              // 2048+1024+512
constexpr int PAT_N   = PAT_POS * C_CH;

// async global->LDS, 16B per lane, dest = wave-uniform base + lane*16
#define GLL16(g, l) __builtin_amdgcn_global_load_lds(                        \
    (const __attribute__((address_space(1))) unsigned int*)(g),              \
    (__attribute__((address_space(3))) unsigned int*)(l), 16, 0, 0)

// == prep: weights fp32 [oc][ic*9+tap] -> f16 hi/lo [oc][tap*256+ic] x3 =====
__global__ __launch_bounds__(256)
void prep_weights_kernel(const float* __restrict__ sw, const float* __restrict__ ew,
                         const float* __restrict__ pw,
                         f16* __restrict__ wTs, f16* __restrict__ wTe,
                         f16* __restrict__ wTsL, f16* __restrict__ wTeL,
                         f16* __restrict__ wTp, f16* __restrict__ wTpL, int n)
{
    int i = blockIdx.x * 256 + threadIdx.x;
    if (i >= n) return;
    const int oc = i / KTOT;
    const int kp = i - oc * KTOT;
    const int tap = kp >> 8;
    const int ic  = kp & 255;
    const int src = oc * KTOT + ic * 9 + tap;
    const float vs = sw[src];
    const f16 hs = (f16)vs;
    wTs[i]  = hs;
    wTsL[i] = (f16)((vs - (float)hs) * 1024.f);
    const float ve = ew[src];
    const f16 he = (f16)ve;
    wTe[i]  = he;
    wTeL[i] = (f16)((ve - (float)he) * 1024.f);
    const float vp = pw[src];
    const f16 hp = (f16)vp;
    wTp[i]  = hp;
    wTpL[i] = (f16)((vp - (float)hp) * 1024.f);
}

// ================= prep: BN scale/shift per tower(2) x level(3) x oc(256) ==
__global__ __launch_bounds__(256)
void prep_bn_kernel(const float* sg, const float* sbb, const float* smm,
                    const float* svv, const float* sb,
                    const float* eg, const float* ebb, const float* emm,
                    const float* evv, const float* eb,
                    float* __restrict__ scale, float* __restrict__ shift)
{
    int i = blockIdx.x * 256 + threadIdx.x;
    if (i >= 1536) return;
    const int tw = i / 768;
    const int r  = i - tw * 768;          // lvl*256 + oc
    const int oc = r & 255;
    float g, bbv, m, v, cb;
    if (tw == 0) { g = sg[r]; bbv = sbb[r]; m = smm[r]; v = svv[r]; cb = sb[oc]; }
    else         { g = eg[r]; bbv = ebb[r]; m = emm[r]; v = evv[r]; cb = eb[oc]; }
    const float inv = 1.0f / sqrtf(v + 1e-5f);
    const float sc = g * inv;
    scale[i] = sc;
    shift[i] = (cb - m) * sc + bbv;
}

// ===================== zero-fill a f16 buffer (x8 groups) ==================
__global__ __launch_bounds__(256)
void zero16_kernel(f16x8* __restrict__ p, int n8)
{
    const int i = blockIdx.x * 256 + threadIdx.x;
    if (i < n8) p[i] = (f16x8){};
}

// ===== fill fpad16 hi/lo: padded-corner HWC f16 [lvlb][36*36][256] =========
__global__ __launch_bounds__(256)
void fpad16_fill_kernel(const float* __restrict__ feat0,
                        const float* __restrict__ feat1,
                        const float* __restrict__ feat2,
                        f16* __restrict__ xH, f16* __restrict__ xL)
{
    const int h    = blockIdx.x;
    const int lvlb = blockIdx.y;
    const int lvl  = lvlb >> 2, b = lvlb & 3;
    const int logW = 7 - lvl, H = 128 >> lvl;
    if (h >= H) return;                    // lvl2: rows h>=32 stay zero
    const int Wv = (H >= 34) ? 34 : 32;    // valid w count
    const int tid = threadIdx.x;
    const float* f = (lvl == 0) ? feat0 : (lvl == 1 ? feat1 : feat2);

    __shared__ float T[34][257];

    const int wl = tid & 31;
    const int cg = tid >> 5;               // 0..7
#pragma unroll
    for (int cb = 0; cb < 32; cb++) {
        const int c = cb * 8 + cg;
        const float* row = f + (((size_t)(b * C_CH + c)) << (2 * logW))
                             + ((size_t)h << logW);
        T[wl][c] = row[wl];
        if (wl < 2 && (wl + 32) < Wv) T[wl + 32][c] = row[wl + 32];
    }
    __syncthreads();
    const size_t rb = ((size_t)lvlb * 1296 + (size_t)(h + 2) * 36 + 2) * 256 + tid;
    for (int w = 0; w < Wv; w++) {
        const float v = T[w][tid];
        const f16 hh = (f16)v;
        xH[rb + (size_t)w * 256] = hh;
        xL[rb + (size_t)w * 256] = (f16)((v - (float)hh) * 1024.f);
    }
}

// ===== transpose-pad: feat fp32 [4][256][H][W] -> f16 HWC padded interior ==
__global__ __launch_bounds__(256)
void pad_hwc_kernel(const float* __restrict__ feat, f16* __restrict__ xT,
                    int H, int logW)
{
    const int W = 1 << logW;
    const int HW = H << logW;
    const int WP = W + 2, HP = H + 2;
    const int tid = threadIdx.x;
    const int nt  = HW >> 6;
    const int b   = blockIdx.x / nt;
    const int p0  = (blockIdx.x - b * nt) * 64;

    __shared__ f16 T[64][264];

    const int cBase = tid >> 4;
    const int pl4   = (tid & 15) * 4;
#pragma unroll
    for (int it = 0; it < 16; it++) {
        const int c = it * 16 + cBase;
        const float4 v = *(const float4*)(feat + (size_t)(b * C_CH + c) * HW + p0 + pl4);
        T[pl4 + 0][c] = (f16)v.x;
        T[pl4 + 1][c] = (f16)v.y;
        T[pl4 + 2][c] = (f16)v.z;
        T[pl4 + 3][c] = (f16)v.w;
    }
    __syncthreads();
    const int pl = tid >> 2;
    const int c0 = (tid & 3) * 64;
    const int p  = p0 + pl;
    const int h  = p >> logW, w = p & (W - 1);
    f16* dst = xT + ((size_t)(b * HP + h + 1) * WP + (w + 1)) * C_CH + c0;
#pragma unroll
    for (int i = 0; i < 64; i += 8)
        *(f16x8*)(dst + i) = *(const f16x8*)&T[pl][c0 + i];
}

// ============== zero border positions of a padded HWC f16 buffer ===========
__global__ __launch_bounds__(256)
void zero_cl_border_kernel(f16* __restrict__ xT, int H, int W, int n)
{
    const int WP = W + 2, HP = H + 2;
    const int BS = 2 * WP + 2 * H;
    int i = blockIdx.x * 256 + threadIdx.x;
    if (i >= n) return;
    const int ch = (i & 7) * 32;
    const int bc = i >> 3;
    const int b  = bc / BS;
    const int e  = bc - b * BS;
    int padpos;
    if (e < WP)            padpos = e;
    else if (e < 2 * WP)   padpos = (H + 1) * WP + (e - WP);
    else {
        const int e2 = e - 2 * WP;
        padpos = ((e2 >> 1) + 1) * WP + ((e2 & 1) ? (W + 1) : 0);
    }
    f16* dst = xT + ((size_t)b * HP * WP + padpos) * C_CH + ch;
    const f16x8 z = {};
#pragma unroll
    for (int j = 0; j < 32; j += 8) *(f16x8*)(dst + j) = z;
}

// =================== MFMA f16 conv3x3 + BN + ReLU (fast path) ==============
// R13-proven schedule: 2-phase dbuf global_load_lds staging, unpadded
// [128][32] tiles, XOR slot-swizzle both sides, XCD-chunked block swizzle.
__global__ __launch_bounds__(256, 3)
void conv_mfma_kernel(const f16* __restrict__ xT, const f16* __restrict__ wT,
                      const float* __restrict__ scale,
                      const float* __restrict__ shift,
                      f16* __restrict__ y, int H, int logW, int opad)
{
    const int W  = 1 << logW;
    const int WP = W + 2, HP = H + 2;
    const int HW = H << logW;
    const int tid  = threadIdx.x;
    const int wv   = tid >> 6, lane = tid & 63;

    // --- XCD-chunked bijective swizzle (nwg % 8 == 0 for all levels) ---
    const int nwg = gridDim.x;
    const int bid = blockIdx.x;
    const int wg  = (bid & 7) * (nwg >> 3) + (bid >> 3);
    const int ocBase = (wg & 1) * 128;     // oc-tiles of one pos-tile adjacent
    const int pBase  = (wg >> 1) * 128;
    const int b    = pBase / HW;
    const int rem0 = pBase - b * HW;

    // 2 x (A[128][32] + B[128][32]) f16 = 32 KB
    __shared__ f16 sbuf[16384];

    f32x4 acc[4][4];
#pragma unroll
    for (int i = 0; i < 4; i++)
#pragma unroll
        for (int j = 0; j < 4; j++) acc[i][j] = (f32x4){0.f, 0.f, 0.f, 0.f};

    // --- staging: per wave, 2 calls A + 2 calls B, 1KB each (lane*16B) ---
    const int lr = lane >> 2, ls = lane & 3;
    const int r0 = (wv * 2) * 16 + lr;
    const int r1 = (wv * 2 + 1) * 16 + lr;
    const int c0s = (ls ^ ((r0 >> 1) & 3)) * 8;
    const int c1s = (ls ^ ((r1 >> 1) & 3)) * 8;
    const f16* aSrc0 = wT + (size_t)(ocBase + r0) * KTOT + c0s;
    const f16* aSrc1 = wT + (size_t)(ocBase + r1) * KTOT + c1s;
    const int pp0 = rem0 + r0, pp1 = rem0 + r1;
    const f16* bSrc0 = xT + ((size_t)(b * HP + (pp0 >> logW) + 1) * WP
                             + (pp0 & (W - 1)) + 1) * C_CH + c0s;
    const f16* bSrc1 = xT + ((size_t)(b * HP + (pp1 >> logW) + 1) * WP
                             + (pp1 & (W - 1)) + 1) * C_CH + c1s;

    // --- fragment ds_read offsets (f16 units), swizzled cols ---
    const int rw = (wv & 1) * 64;
    const int cw = (wv >> 1) * 64;
    const int lm = lane & 15, lq = lane >> 4;
    int aOff[4], bOff[4];
#pragma unroll
    for (int mi = 0; mi < 4; mi++) {
        const int R = rw + mi * 16 + lm;
        aOff[mi] = R * 32 + ((lq ^ ((R >> 1) & 3)) << 3);
    }
#pragma unroll
    for (int ni = 0; ni < 4; ni++) {
        const int R = cw + ni * 16 + lm;
        bOff[ni] = 4096 + R * 32 + ((lq ^ ((R >> 1) & 3)) << 3);
    }

    auto STAGE = [&](int kn, int nb) {
        const int tap = kn >> 8;
        const int kh  = tap / 3;
        const int kw  = tap - 3 * kh;
        const int tOff = ((kh - 1) * WP + (kw - 1)) * C_CH + (kn & 255);
        f16* lb = &sbuf[nb * 8192 + wv * 1024];          // wave-uniform base
        GLL16(aSrc0 + kn, lb);
        GLL16(aSrc1 + kn, lb + 512);
        GLL16(bSrc0 + tOff, lb + 4096);
        GLL16(bSrc1 + tOff, lb + 4096 + 512);
    };

    STAGE(0, 0);
    __syncthreads();                       // drains vmcnt(0) before s_barrier
    int cur = 0;
    for (int k0 = 0; k0 < KTOT; k0 += 32) {
        if (k0 + 32 < KTOT) STAGE(k0 + 32, cur ^ 1);   // overlap with compute
        const f16* sb = &sbuf[cur * 8192];
        f16x8 af[4], bf[4];
#pragma unroll
        for (int mi = 0; mi < 4; mi++) af[mi] = *(const f16x8*)(sb + aOff[mi]);
#pragma unroll
        for (int ni = 0; ni < 4; ni++) bf[ni] = *(const f16x8*)(sb + bOff[ni]);
#pragma unroll
        for (int mi = 0; mi < 4; mi++)
#pragma unroll
            for (int ni = 0; ni < 4; ni++)
                acc[mi][ni] = __builtin_amdgcn_mfma_f32_16x16x32_f16(
                    af[mi], bf[ni], acc[mi][ni], 0, 0, 0);
        __syncthreads();                   // drain next-tile loads + flip
        cur ^= 1;
    }

    float sc[4][4], sh[4][4];
#pragma unroll
    for (int mi = 0; mi < 4; mi++)
#pragma unroll
        for (int r = 0; r < 4; r++) {
            const int oc = ocBase + rw + mi * 16 + lq * 4 + r;
            sc[mi][r] = scale[oc];
            sh[mi][r] = shift[oc];
        }
#pragma unroll
    for (int ni = 0; ni < 4; ni++) {
        const int pp = rem0 + cw + ni * 16 + lm;
        size_t dst;
        if (opad) {
            const int h2 = pp >> logW, w2 = pp & (W - 1);
            dst = ((size_t)(b * HP + h2 + 1) * WP + (w2 + 1)) * C_CH;
        } else {
            dst = (size_t)(pBase + cw + ni * 16 + lm) * C_CH;
        }
#pragma unroll
        for (int mi = 0; mi < 4; mi++) {
            const int ocb = ocBase + rw + mi * 16 + lq * 4;
            f16x4 o;
#pragma unroll
            for (int r = 0; r < 4; r++)
                o[r] = (f16)fmaxf(fmaf(acc[mi][ni][r], sc[mi][r], sh[mi][r]), 0.f);
            *(f16x4*)(y + dst + ocb) = o;
        }
    }
}

// ============ ehead 1x1 + sigmoid from dense HWC f16 ex -> em map ==========
__global__ __launch_bounds__(256)
void ehead_em_f16_kernel(const f16* __restrict__ ex, const float* __restrict__ ehw,
                         const float* __restrict__ ehb, float* __restrict__ em)
{
    const int wv   = threadIdx.x >> 6;
    const int lane = threadIdx.x & 63;
    const int posBase = (blockIdx.x * 4 + wv) * 8;
    const int sp = lane >> 3;
    const int t  = lane & 7;
    const int cg = t * 32;
    const f16* base = ex + (size_t)(posBase + sp) * C_CH + cg;
    float s = 0.f;
#pragma unroll
    for (int i = 0; i < 32; i += 8) {
        const f16x8 v = *(const f16x8*)(base + i);
#pragma unroll
        for (int j = 0; j < 8; j++)
            s = fmaf((float)v[j], ehw[cg + i + j], s);
    }
    s += __shfl_xor(s, 1);
    s += __shfl_xor(s, 2);
    s += __shfl_xor(s, 4);
    if (t == 0) em[posBase + sp] = 1.0f / (1.0f + expf(-(s + ehb[0])));
}

// ====== EXACT paired-f16 MFMA, FULL-K, 64oc x 64pos, fused epilogues =======
// 1D grid, XCD-chunked; wgs&3 = oc quarter (adjacent -> B L2 reuse x4).
// share: 912 blocks; ent: 768 blocks. Dbuf staging (proven schedule).
template<bool IS_SHARE>
__global__ __launch_bounds__(256, 2)
void exact_full_kernel(const f16* __restrict__ xHg, const f16* __restrict__ xLg,
                       const f16* __restrict__ wH, const f16* __restrict__ wL,
                       const float* __restrict__ scale,
                       const float* __restrict__ shift,
                       float* __restrict__ xsp,
                       f16* __restrict__ xOH, f16* __restrict__ xOL,
                       float* __restrict__ apePart, const float* __restrict__ ehw)
{
    constexpr int NTL    = IS_SHARE ? 19 : 16;
    constexpr int IPITCH = IS_SHARE ? 36 : 34;
    constexpr int IPLANE = IS_SHARE ? 1296 : 1156;

    const int tid  = threadIdx.x;
    const int wv   = tid >> 6, lane = tid & 63;

    // --- XCD-chunked bijective swizzle; oc-quarters adjacent ---
    const int nwg = gridDim.x;             // 912 or 768, % 8 == 0
    const int bid = blockIdx.x;
    const int wgs = (bid & 7) * (nwg >> 3) + (bid >> 3);
    const int ocq = wgs & 3;
    const int ti  = wgs >> 2;
    const int lvlb = ti / NTL;
    const int tile = ti - lvlb * NTL;
    const int posBase = tile * 64;
    const int ocBase  = ocq * 64;
    const int lvl  = lvlb >> 2;

    // 2 x (AsH|AsL|BsH|BsL each [64][32]) = 32 KB; epilogue reuses region
    __shared__ f16 sbuf[16384];

    f32x4 accH[2][2], accX[2][2];
#pragma unroll
    for (int i = 0; i < 2; i++)
#pragma unroll
        for (int j = 0; j < 2; j++) {
            accH[i][j] = (f32x4){0.f, 0.f, 0.f, 0.f};
            accX[i][j] = (f32x4){0.f, 0.f, 0.f, 0.f};
        }

    // --- staging: per wave 4 GLL16 (A-H, A-L, B-H, B-L), rows wv*16..+15 ---
    const int lr = lane >> 2, ls = lane & 3;
    const int rA = wv * 16 + lr;                   // 0..63
    const int cAs = (ls ^ ((rA >> 1) & 3)) * 8;    // pre-swizzled col
    const f16* aSrcH = wH + (size_t)(ocBase + rA) * KTOT + cAs;
    const f16* aSrcL = wL + (size_t)(ocBase + rA) * KTOT + cAs;

    int n = posBase + rA;
    if (IS_SHARE && n > 1155) n = 1155;            // tail tile clamp (masked)
    int po;
    if (IS_SHARE) { const int ph = n / 34; po = ph * 36 + (n - ph * 34); }
    else          { po = (n >> 5) * 34 + (n & 31); }
    const f16* bSrcH = xHg + ((size_t)lvlb * IPLANE + po) * 256 + cAs;
    const f16* bSrcL = xLg + ((size_t)lvlb * IPLANE + po) * 256 + cAs;

    // --- fragment ds_read offsets (f16 units), swizzled cols ---
    const int rw = (wv & 1) * 32;                  // oc within 64
    const int cw = (wv >> 1) * 32;                 // pos within 64
    const int lm = lane & 15, lq = lane >> 4;
    int aOff[2], bOff[2];
#pragma unroll
    for (int mi = 0; mi < 2; mi++) {
        const int R = rw + mi * 16 + lm;
        aOff[mi] = R * 32 + ((lq ^ ((R >> 1) & 3)) << 3);
    }
#pragma unroll
    for (int ni = 0; ni < 2; ni++) {
        const int R = cw + ni * 16 + lm;
        bOff[ni] = R * 32 + ((lq ^ ((R >> 1) & 3)) << 3);
    }

    auto STAGE = [&](int kn, int nb) {
        const int tap = kn >> 8;
        const int th  = tap / 3;
        const int tOff = (th * IPITCH + (tap - 3 * th)) * 256 + (kn & 255);
        f16* lb = &sbuf[nb * 8192 + wv * 512];     // wave-uniform bases
        GLL16(aSrcH + kn, lb);
        GLL16(aSrcL + kn, lb + 2048);
        GLL16(bSrcH + tOff, lb + 4096);
        GLL16(bSrcL + tOff, lb + 6144);
    };

    STAGE(0, 0);
    __syncthreads();                       // drains vmcnt(0): tile 0 landed
    int cur = 0;
    for (int ko = 0; ko < KTOT; ko += 32) {
        if (ko + 32 < KTOT) STAGE(ko + 32, cur ^ 1);   // overlap with compute
        const f16* sb = &sbuf[cur * 8192];
        f16x8 aH[2], aL[2];
#pragma unroll
        for (int mi = 0; mi < 2; mi++) {
            aH[mi] = *(const f16x8*)(sb + aOff[mi]);
            aL[mi] = *(const f16x8*)(sb + 2048 + aOff[mi]);
        }
#pragma unroll
        for (int ni = 0; ni < 2; ni++) {
            const f16x8 bh = *(const f16x8*)(sb + 4096 + bOff[ni]);
            const f16x8 bl = *(const f16x8*)(sb + 6144 + bOff[ni]);
#pragma unroll
            for (int mi = 0; mi < 2; mi++)
                accH[mi][ni] = __builtin_amdgcn_mfma_f32_16x16x32_f16(
                    aH[mi], bh, accH[mi][ni], 0, 0, 0);
#pragma unroll
            for (int mi = 0; mi < 2; mi++)
                accX[mi][ni] = __builtin_amdgcn_mfma_f32_16x16x32_f16(
                    aH[mi], bl, accX[mi][ni], 0, 0, 0);
#pragma unroll
            for (int mi = 0; mi < 2; mi++)
                accX[mi][ni] = __builtin_amdgcn_mfma_f32_16x16x32_f16(
                    aL[mi], bh, accX[mi][ni], 0, 0, 0);
        }
        __syncthreads();                   // drain next-tile loads + flip
        cur ^= 1;
    }

    if constexpr (IS_SHARE) {
        // BN+ReLU+mask; write xsp fp32 CHW; stage hi/lo into LDS transpose
        // buf with stride 72 f16 (144B rows: 16B-aligned, 2-way banks).
#pragma unroll
        for (int mi = 0; mi < 2; mi++)
#pragma unroll
            for (int r = 0; r < 4; r++) {
                const int chl = rw + mi * 16 + lq * 4 + r;    // 0..63
                const int oc  = ocBase + chl;
                const float sc = scale[lvl * 256 + oc];
                const float sh = shift[lvl * 256 + oc];
#pragma unroll
                for (int ni = 0; ni < 2; ni++) {
                    const int pl  = cw + ni * 16 + lm;        // 0..63
                    const int nn  = posBase + pl;
                    const float val = accH[mi][ni][r]
                                    + accX[mi][ni][r] * (1.0f / 1024.0f);
                    const int ph = nn / 34;
                    const int pw = nn - ph * 34;
                    const bool valid = (nn < 1156) && (ph >= 1) && (pw >= 1) &&
                                       (lvl < 2 || (ph <= 32 && pw <= 32));
                    const float o = valid ? fmaxf(fmaf(val, sc, sh), 0.f) : 0.f;
                    if (nn < 1156)
                        xsp[((size_t)(lvlb * 256 + oc)) * 1156 + nn] = o;
                    const f16 h = (f16)o;
                    sbuf[pl * 72 + chl]        = h;
                    sbuf[4608 + pl * 72 + chl] = (f16)((o - (float)h) * 1024.f);
                }
            }
        __syncthreads();
        const int p  = tid >> 2;
        const int cg = (tid & 3) * 16;
        const int n2 = posBase + p;
        if (n2 < 1156) {
            const size_t gb = ((size_t)lvlb * 1156 + n2) * 256 + ocBase + cg;
            *(f16x8*)(xOH + gb)     = *(const f16x8*)(sbuf + p * 72 + cg);
            *(f16x8*)(xOH + gb + 8) = *(const f16x8*)(sbuf + p * 72 + cg + 8);
            *(f16x8*)(xOL + gb)     = *(const f16x8*)(sbuf + 4608 + p * 72 + cg);
            *(f16x8*)(xOL + gb + 8) = *(const f16x8*)(sbuf + 4608 + p * 72 + cg + 8);
        }
    } else {
        // BN+ReLU; ehead contraction over this block's 64-oc slice
        float* pa = (float*)sbuf;          // [64 cells][8 contributors]
        float pni[2] = {0.f, 0.f};
#pragma unroll
        for (int mi = 0; mi < 2; mi++)
#pragma unroll
            for (int r = 0; r < 4; r++) {
                const int oc = ocBase + rw + mi * 16 + lq * 4 + r;
                const float sc = scale[768 + lvl * 256 + oc];
                const float sh = shift[768 + lvl * 256 + oc];
                const float w  = ehw[oc];
#pragma unroll
                for (int ni = 0; ni < 2; ni++) {
                    const float val = accH[mi][ni][r]
                                    + accX[mi][ni][r] * (1.0f / 1024.0f);
                    pni[ni] = fmaf(w, fmaxf(fmaf(val, sc, sh), 0.f), pni[ni]);
                }
            }
        const int slot = lq + 4 * (wv & 1);
#pragma unroll
        for (int ni = 0; ni < 2; ni++)
            pa[(cw + ni * 16 + lm) * 8 + slot] = pni[ni];
        __syncthreads();
        if (tid < 64) {
            float s = pa[tid * 8];
#pragma unroll
            for (int j = 1; j < 8; j++) s += pa[tid * 8 + j];
            apePart[(size_t)ocq * 12288 + lvlb * 1024 + posBase + tid] = s;
        }
    }
}

// ======= ape finalize: sum 4 oc-quarter partials + bias + sigmoid ==========
__global__ __launch_bounds__(256)
void ape_fin_kernel(const float* __restrict__ apePart,
                    const float* __restrict__ ehb, float* __restrict__ ape)
{
    const int i = blockIdx.x * 256 + threadIdx.x;
    if (i >= 12288) return;
    float s = apePart[i];
    s += apePart[12288 + i];
    s += apePart[24576 + i];
    s += apePart[36864 + i];
    ape[i] = 1.0f / (1.0f + expf(-(s + ehb[0])));
}

// ===================== top-k, all levels (grid 12) =========================
__global__ __launch_bounds__(1024)
void topk_all_kernel(const float* __restrict__ ape, const int* __restrict__ coords,
                     int* __restrict__ xy_int, float* __restrict__ out,
                     int xo0, int xo1, int xo2)
{
    const int lvl = blockIdx.x >> 2;
    const int b   = blockIdx.x & 3;
    const int nk  = 512 >> lvl;
    const int tid = threadIdx.x;
    __shared__ unsigned long long keys[1024];

    const int rr = coords[tid] & 31;
    const int cc0 = coords[1024 + tid] & 31;
    const float v = ape[lvl * 4096 + (b << 10) + (rr << 5) + cc0];
    unsigned u = __float_as_uint(v);
    unsigned mono = (u & 0x80000000u) ? ~u : (u | 0x80000000u);
    keys[tid] = (((unsigned long long)(~mono)) << 32) | (unsigned)tid;
    __syncthreads();

    for (int k = 2; k <= 1024; k <<= 1) {
        for (int j = k >> 1; j > 0; j >>= 1) {
            const int ixj = tid ^ j;
            if (ixj > tid) {
                const bool up = ((tid & k) == 0);
                const unsigned long long a = keys[tid], c = keys[ixj];
                if ((a > c) == up) { keys[tid] = c; keys[ixj] = a; }
            }
            __syncthreads();
        }
    }

    if (tid < nk) {
        const int i  = (int)(keys[tid] & 0x3FFu);
        const int r  = coords[i] & 31;
        const int c  = coords[1024 + i] & 31;
        const int intOff = 8192 - (8192 >> lvl);
        const int o  = intOff + (b * nk + tid) * 2;
        xy_int[o]     = r;
        xy_int[o + 1] = c;
        const int xo = (lvl == 0) ? xo0 : (lvl == 1 ? xo1 : xo2);
        out[xo + (b * nk + tid) * 2]     = (float)r;
        out[xo + (b * nk + tid) * 2 + 1] = (float)c;
    }
}

// ====== pat conv at top-k: paired-f16 MFMA, 32pos x 64oc, split-K x2 =======
// 1D grid 896 = [ti112][ocq4][z2] via XCD-chunked swizzle (z,ocq adjacent).
// B gather from xspH/xspL (f16 hi/lo HWC); pofs = r*34+c (corner), tap
// addressing identical to exact_full<ent>. Raw conv partials out (BN in
// pat_reduce, fixed order). Dbuf __syncthreads schedule (proven).
__global__ __launch_bounds__(256, 2)
void pat_mfma_kernel(const f16* __restrict__ xHg, const f16* __restrict__ xLg,
                     const f16* __restrict__ wH, const f16* __restrict__ wL,
                     const int* __restrict__ xy_int,
                     float* __restrict__ part)
{
    const int tid = threadIdx.x;
    const int wv  = tid >> 6, lane = tid & 63;
    const int nwg = gridDim.x;             // 896
    const int bid = blockIdx.x;
    const int wgs = (bid & 7) * (nwg >> 3) + (bid >> 3);
    const int z   = wgs & 1;
    const int ocq = (wgs >> 1) & 3;
    const int ti  = wgs >> 3;              // 0..111
    int lvl, pL;
    if (ti < 64)      { lvl = 0; pL = ti * 32; }
    else if (ti < 96) { lvl = 1; pL = (ti - 64) * 32; }
    else              { lvl = 2; pL = (ti - 96) * 32; }
    const int nk   = 512 >> lvl;
    const int bb   = pL / nk;
    const int lvlb = lvl * 4 + bb;
    const int intOff   = 8192 - (8192 >> lvl);
    const int posStart = 4096 - (4096 >> lvl);
    const int ocBase = ocq * 64;
    const int kStart = z * 1152;

    // 2 x (AH[64][32] | AL[64][32] | BH[32][32] | BL[32][32]) = 24 KB
    __shared__ f16 sbuf[12288];
    __shared__ int pofs[32];

    if (tid < 32) {
        const int n = pL + tid;
        const int r = xy_int[intOff + n * 2]     & 31;
        const int c = xy_int[intOff + n * 2 + 1] & 31;
        pofs[tid] = r * 34 + c;            // corner of 3x3 window (padded)
    }
    __syncthreads();

    f32x4 accH[2], accX[2];
#pragma unroll
    for (int i = 0; i < 2; i++) {
        accH[i] = (f32x4){0.f, 0.f, 0.f, 0.f};
        accX[i] = (f32x4){0.f, 0.f, 0.f, 0.f};
    }

    const int lr = lane >> 2, ls = lane & 3;
    // A: wave wv stages oc rows wv*16..+15 (hi and lo)
    const int rA  = wv * 16 + lr;
    const int cAs = (ls ^ ((rA >> 1) & 3)) * 8;
    const f16* aSrcH = wH + (size_t)(ocBase + rA) * KTOT + kStart + cAs;
    const f16* aSrcL = wL + (size_t)(ocBase + rA) * KTOT + kStart + cAs;
    // B: waves 0,1 stage B-H rows 0-15/16-31; waves 2,3 stage B-L same rows
    const int rB  = (wv & 1) * 16 + lr;    // 0..31
    const int cBs = (ls ^ ((rB >> 1) & 3)) * 8;
    const f16* bBase = (wv < 2) ? xHg : xLg;
    const f16* bSrc = bBase + ((size_t)lvlb * 1156 + pofs[rB]) * 256 + cBs;
    const int bDst = ((wv < 2) ? 4096 : 5120) + (wv & 1) * 512;

    // frag offsets
    const int rw = (wv & 1) * 32;          // oc within 64
    const int pw = (wv >> 1) * 16;         // pos within 32
    const int lm = lane & 15, lq = lane >> 4;
    int aOff[2];
#pragma unroll
    for (int mi = 0; mi < 2; mi++) {
        const int R = rw + mi * 16 + lm;
        aOff[mi] = R * 32 + ((lq ^ ((R >> 1) & 3)) << 3);
    }
    const int Rb = pw + lm;
    const int bOff = 4096 + Rb * 32 + ((lq ^ ((Rb >> 1) & 3)) << 3);

    auto STAGE = [&](int kRel, int nb) {
        const int kAbs = kStart + kRel;
        const int tap  = kAbs >> 8;
        const int th   = tap / 3;
        const int tOff = (th * 34 + (tap - 3 * th)) * 256 + (kAbs & 255);
        f16* base = &sbuf[nb * 6144];
        GLL16(aSrcH + kRel, base + wv * 512);            // A-H
        GLL16(aSrcL + kRel, base + 2048 + wv * 512);     // A-L
        GLL16(bSrc + tOff,  base + bDst);                // B (H or L half)
    };

    STAGE(0, 0);
    __syncthreads();                       // drains vmcnt(0): tile 0 landed
    int cur = 0;
    for (int ko = 0; ko < 1152; ko += 32) {
        if (ko + 32 < 1152) STAGE(ko + 32, cur ^ 1);   // overlap with compute
        const f16* sb = &sbuf[cur * 6144];
        f16x8 aH[2], aL[2];
#pragma unroll
        for (int mi = 0; mi < 2; mi++) {
            aH[mi] = *(const f16x8*)(sb + aOff[mi]);
            aL[mi] = *(const f16x8*)(sb + 2048 + aOff[mi]);
        }
        const f16x8 bh = *(const f16x8*)(sb + bOff);
        const f16x8 bl = *(const f16x8*)(sb + 1024 + bOff);
#pragma unroll
        for (int mi = 0; mi < 2; mi++)
            accH[mi] = __builtin_amdgcn_mfma_f32_16x16x32_f16(
                aH[mi], bh, accH[mi], 0, 0, 0);
#pragma unroll
        for (int mi = 0; mi < 2; mi++)
            accX[mi] = __builtin_amdgcn_mfma_f32_16x16x32_f16(
                aH[mi], bl, accX[mi], 0, 0, 0);
#pragma unroll
        for (int mi = 0; mi < 2; mi++)
            accX[mi] = __builtin_amdgcn_mfma_f32_16x16x32_f16(
                aL[mi], bh, accX[mi], 0, 0, 0);
        __syncthreads();                   // drain next-tile loads + flip
        cur ^= 1;
    }

    // raw conv partials, [pos][256] fp32; BN applied in pat_reduce
    float* op = part + (size_t)z * PAT_N
              + (size_t)(posStart + pL + pw + lm) * C_CH + ocBase;
#pragma unroll
    for (int mi = 0; mi < 2; mi++)
#pragma unroll
        for (int r = 0; r < 4; r++)
            op[rw + mi * 16 + lq * 4 + r] =
                accH[mi][r] + accX[mi][r] * (1.0f / 1024.0f);
}

// ===== pat split-K x2 reduce (fixed order) + BN + ReLU -> af [3584][256] ===
__global__ __launch_bounds__(256)
void pat_reduce_kernel(const float* __restrict__ part,
                       const float* __restrict__ cb,
                       const float* __restrict__ bng, const float* __restrict__ bnb,
                       const float* __restrict__ bnm, const float* __restrict__ bnv,
                       float* __restrict__ af)
{
    const int i4 = (blockIdx.x * 256 + threadIdx.x) * 4;
    if (i4 >= PAT_N) return;
    const int pos = i4 >> 8;
    const int oc0 = i4 & 255;
    const int lvl = (pos < 2048) ? 0 : (pos < 3072 ? 1 : 2);
    float4 s = *(const float4*)(part + i4);
    {
        const float4 t = *(const float4*)(part + (size_t)PAT_N + i4);
        s.x += t.x; s.y += t.y; s.z += t.z; s.w += t.w;
    }
    const float4 g  = *(const float4*)(bng + lvl * 256 + oc0);
    const float4 bb = *(const float4*)(bnb + lvl * 256 + oc0);
    const float4 m  = *(const float4*)(bnm + lvl * 256 + oc0);
    const float4 v  = *(const float4*)(bnv + lvl * 256 + oc0);
    const float4 cb4 = *(const float4*)(cb + oc0);
    float4 o;
    {
        float inv = 1.0f / sqrtf(v.x + 1e-5f); float sc = g.x * inv;
        o.x = fmaxf(fmaf(s.x, sc, (cb4.x - m.x) * sc + bb.x), 0.f);
        inv = 1.0f / sqrtf(v.y + 1e-5f); sc = g.y * inv;
        o.y = fmaxf(fmaf(s.y, sc, (cb4.y - m.y) * sc + bb.y), 0.f);
        inv = 1.0f / sqrtf(v.z + 1e-5f); sc = g.z * inv;
        o.z = fmaxf(fmaf(s.z, sc, (cb4.z - m.z) * sc + bb.z), 0.f);
        inv = 1.0f / sqrtf(v.w + 1e-5f); sc = g.w * inv;
        o.w = fmaxf(fmaf(s.w, sc, (cb4.w - m.w) * sc + bb.w), 0.f);
    }
    *(float4*)(af + i4) = o;
}

// ============ head + final boxes, all levels (grid 3584) ===================
__global__ __launch_bounds__(256)
void head_final_all_kernel(const float* __restrict__ af, const float* __restrict__ hw,
                           const float* __restrict__ hb, const int* __restrict__ xy_int,
                           float* __restrict__ out, int fo0, int fo1, int fo2)
{
    const int pos = blockIdx.x;
    const int lvl = (pos < 2048) ? 0 : (pos < 3072 ? 1 : 2);
    const int local = pos - (4096 - (4096 >> lvl));
    const int intOff = 8192 - (8192 >> lvl);
    const int fo = (lvl == 0) ? fo0 : (lvl == 1 ? fo1 : fo2);
    const int tid  = threadIdx.x;
    const int j4   = tid >> 6;
    const int lane = tid & 63;
    const float* a = af + (size_t)pos * C_CH;
    const float* w = hw + j4 * C_CH;
    float sum = 0.f;
#pragma unroll
    for (int i = 0; i < 4; i++)
        sum = fmaf(a[lane + 64 * i], w[lane + 64 * i], sum);
#pragma unroll
    for (int off = 32; off > 0; off >>= 1) sum += __shfl_down(sum, off);
    if (lane == 0) {
        const float pc = 1.0f / (1.0f + expf(-(sum + hb[j4])));
        const float ax = (float)xy_int[intOff + local * 2];
        const float ay = (float)xy_int[intOff + local * 2 + 1];
        float val;
        if      (j4 == 0) val = ax - 16.0f * pc;
        else if (j4 == 1) val = ay - 16.0f * pc;
        else if (j4 == 2) val = ax + 16.0f * pc;
        else              val = ay + 16.0f * pc;
        out[fo + local * 4 + j4] = val;
    }
}

// ============================== launcher ===================================
extern "C" void kernel_launch(void* const* d_in, const int* in_sizes, int n_in,
                              void* d_out, int out_size, void* d_ws, size_t ws_size,
                              hipStream_t stream) {
    const float* feat[3] = {(const float*)d_in[0], (const float*)d_in[1],
                            (const float*)d_in[2]};
    const int*   coords  = (const int*)d_in[3];
    const float* sw  = (const float*)d_in[4];
    const float* sb  = (const float*)d_in[5];
    const float* sg  = (const float*)d_in[6];
    const float* sbb = (const float*)d_in[7];
    const float* smm = (const float*)d_in[8];
    const float* svv = (const float*)d_in[9];
    const float* ew  = (const float*)d_in[10];
    const float* eb  = (const float*)d_in[11];
    const float* eg  = (const float*)d_in[12];
    const float* ebb = (const float*)d_in[13];
    const float* emm = (const float*)d_in[14];
    const float* evv = (const float*)d_in[15];
    const float* pw  = (const float*)d_in[16];
    const float* pb  = (const float*)d_in[17];
    const float* pg  = (const float*)d_in[18];
    const float* pbb = (const float*)d_in[19];
    const float* pmm = (const float*)d_in[20];
    const float* pvv = (const float*)d_in[21];
    const float* ehw = (const float*)d_in[22];
    const float* ehb = (const float*)d_in[23];
    const float* hww = (const float*)d_in[24];
    const float* hbb = (const float*)d_in[25];

    float* out = (float*)d_out;
    char*  ws  = (char*)d_ws;

    // ---- workspace layout (bytes from ws) ----
    f16*   wTs    = (f16*)(ws);                         // 0        (1.18MB)
    f16*   wTe    = (f16*)(ws + 1310720);
    f16*   wTsL   = (f16*)(ws + 2621440);
    f16*   wTeL   = (f16*)(ws + 3932160);
    float* scales = (float*)(ws + 5242880);
    float* shifts = (float*)(ws + 5251072);
    // exact path
    f16*   fpadH  = (f16*)(ws + 6291456);               // 6MB   (7.96MB)
    f16*   fpadL  = (f16*)(ws + 14254080);              // contiguous after H
    float* patPart= (float*)(ws + 6291456);             // reuses fpad16 (dead);
                                                        // 2 x 3.67MB = 7.34MB
    float* af     = (float*)(ws + 23068672);            // 22MB  (3.5MB)
    f16*   wTp    = (f16*)(ws + 27262976);              // exact-path-only; the
    f16*   wTpL   = (f16*)(ws + 28573696);              // fast path clobbers
                                                        // later (stream order)
    f16*   xspH   = (f16*)(ws + 90177536);              // 86MB  (6.8MB)
    f16*   xspL   = (f16*)(ws + 97280000);
    float* xsp    = (float*)(ws + 104857600);           // 100MB (13.6MB)
    float* ape    = (float*)(ws + 119537664);           // 114MB (48KB)
    int*   xy_int = (int*)  (ws + 119603200);           // (32KB)
    float* apePart= (float*)(ws + 119668736);           // (192KB)
    // fast path (runs after exact path; reuses dead exact regions)
    f16*   featT  = (f16*)(ws + 27262976);              // 26MB (34.6MB, lvl0)
    f16*   xsT    = (f16*)(ws + 65011712);              // 62MB (34.6MB) disjoint
    f16*   exT    = (f16*)(ws + 27262976);              // reuses featT (dead)

    const int Hs[3]    = {128, 64, 32};
    const int logWs[3] = {7, 6, 5};
    const int nks[3]   = {512, 256, 128};

    size_t off = 0;
    size_t emOff[3], finOff[3], xyOff[3];
    for (int l = 0; l < 3; l++) {
        const int HW = Hs[l] * Hs[l];
        emOff[l]  = off; off += (size_t)4 * HW;
        finOff[l] = off; off += (size_t)4 * nks[l] * 4;
        xyOff[l]  = off; off += (size_t)4 * nks[l] * 2;
    }

    // -------- prep --------
    prep_weights_kernel<<<(C_CH * KTOT + 255) / 256, 256, 0, stream>>>(
        sw, ew, pw, wTs, wTe, wTsL, wTeL, wTp, wTpL, C_CH * KTOT);
    prep_bn_kernel<<<6, 256, 0, stream>>>(sg, sbb, smm, svv, sb,
                                          eg, ebb, emm, evv, eb, scales, shifts);

    // -------- exact path --------
    zero16_kernel<<<(995328 + 255) / 256, 256, 0, stream>>>((f16x8*)fpadH, 995328);
    fpad16_fill_kernel<<<dim3(34, 12), 256, 0, stream>>>(
        feat[0], feat[1], feat[2], fpadH, fpadL);
    exact_full_kernel<true><<<912, 256, 0, stream>>>(
        fpadH, fpadL, wTs, wTsL, scales, shifts, xsp, xspH, xspL,
        nullptr, nullptr);
    exact_full_kernel<false><<<768, 256, 0, stream>>>(
        xspH, xspL, wTe, wTeL, scales, shifts, nullptr, nullptr, nullptr,
        apePart, ehw);
    ape_fin_kernel<<<48, 256, 0, stream>>>(apePart, ehb, ape);
    topk_all_kernel<<<12, 1024, 0, stream>>>(
        ape, coords, xy_int, out, (int)xyOff[0], (int)xyOff[1], (int)xyOff[2]);
    pat_mfma_kernel<<<896, 256, 0, stream>>>(
        xspH, xspL, wTp, wTpL, xy_int, patPart);
    pat_reduce_kernel<<<(PAT_N / 1024), 256, 0, stream>>>(
        patPart, pb, pg, pbb, pmm, pvv, af);
    head_final_all_kernel<<<PAT_POS, 256, 0, stream>>>(
        af, hww, hbb, xy_int, out, (int)finOff[0], (int)finOff[1], (int)finOff[2]);

    // -------- fast path (f16 MFMA), per level --------
    for (int lvl = 0; lvl < 3; lvl++) {
        const int H = Hs[lvl], logW = logWs[lvl];
        const int W = H;
        const int HW = H << logW;
        const int WP = W + 2;
        const int nbord = 4 * (2 * WP + 2 * H) * 8;

        pad_hwc_kernel<<<4 * HW / 64, 256, 0, stream>>>(feat[lvl], featT, H, logW);
        zero_cl_border_kernel<<<(nbord + 255) / 256, 256, 0, stream>>>(
            featT, H, W, nbord);
        zero_cl_border_kernel<<<(nbord + 255) / 256, 256, 0, stream>>>(
            xsT, H, W, nbord);
        dim3 gconv((4 * HW / 128) * 2);     // 1D: wg&1 = oc tile, wg>>1 = pos
        conv_mfma_kernel<<<gconv, 256, 0, stream>>>(
            featT, wTs, scales + lvl * 256, shifts + lvl * 256, xsT, H, logW, 1);
        conv_mfma_kernel<<<gconv, 256, 0, stream>>>(
            xsT, wTe, scales + 768 + lvl * 256, shifts + 768 + lvl * 256,
            exT, H, logW, 0);
        ehead_em_f16_kernel<<<4 * HW / 32, 256, 0, stream>>>(
            exT, ehw, ehb, out + emOff[lvl]);
    }
}

// Round 10
// 682.322 us; speedup vs baseline: 1.3861x; 1.1688x over previous
//
#include <hip/hip_runtime.h>
#include <cstdint>
#include <cstddef>

// ---------------------------------------------------------------------------
// PatchModule R16 — dead/redundant traffic elimination (conv & exact GEMM
// schedules untouched from the R15-proven state):
//   1) xsp fp32 write (13.6MB) deleted: only consumer was old sparse_pat;
//      pat_mfma reads xspH/L. xspH/L remain bit-identical -> ape unchanged.
//   2) ehead fused into ent-conv epilogue: exT (33.5MB w + 33.5MB r @lvl0)
//      eliminated; blocks LDS-reduce their 128-oc half into emPart[2][4HW]
//      (512KB, dead fpad region); em_fin = 2-way sum + sigmoid. em now fp32
//      epilogue (error shrinks; em not used for top-k ordering).
//   3) lvl2 fast path deleted: em lvl2 == ape lvl2 slice exactly (same dense
//      32x32 grid, same math, higher precision) -> 16-block copy.
// FAST PATH conv & EXACT PATH MFMA schedules: R13/R15-proven, byte-identical.
// All gathered indices masked &31 (rocprof replay poison safety).
// ---------------------------------------------------------------------------

typedef _Float16 f16;
typedef _Float16 f16x4 __attribute__((ext_vector_type(4)));
typedef _Float16 f16x8 __attribute__((ext_vector_type(8)));
typedef float    f32x4 __attribute__((ext_vector_type(4)));

constexpr int C_CH = 256;
constexpr int KTOT = 2304;
constexpr int PAT_POS = 3584;              // 2048+1024+512
constexpr int PAT_N   = PAT_POS * C_CH;

// async global->LDS, 16B per lane, dest = wave-uniform base + lane*16
#define GLL16(g, l) __builtin_amdgcn_global_load_lds(                        \
    (const __attribute__((address_space(1))) unsigned int*)(g),              \
    (__attribute__((address_space(3))) unsigned int*)(l), 16, 0, 0)

// == prep: weights fp32 [oc][ic*9+tap] -> f16 hi/lo [oc][tap*256+ic] x3 =====
__global__ __launch_bounds__(256)
void prep_weights_kernel(const float* __restrict__ sw, const float* __restrict__ ew,
                         const float* __restrict__ pw,
                         f16* __restrict__ wTs, f16* __restrict__ wTe,
                         f16* __restrict__ wTsL, f16* __restrict__ wTeL,
                         f16* __restrict__ wTp, f16* __restrict__ wTpL, int n)
{
    int i = blockIdx.x * 256 + threadIdx.x;
    if (i >= n) return;
    const int oc = i / KTOT;
    const int kp = i - oc * KTOT;
    const int tap = kp >> 8;
    const int ic  = kp & 255;
    const int src = oc * KTOT + ic * 9 + tap;
    const float vs = sw[src];
    const f16 hs = (f16)vs;
    wTs[i]  = hs;
    wTsL[i] = (f16)((vs - (float)hs) * 1024.f);
    const float ve = ew[src];
    const f16 he = (f16)ve;
    wTe[i]  = he;
    wTeL[i] = (f16)((ve - (float)he) * 1024.f);
    const float vp = pw[src];
    const f16 hp = (f16)vp;
    wTp[i]  = hp;
    wTpL[i] = (f16)((vp - (float)hp) * 1024.f);
}

// ================= prep: BN scale/shift per tower(2) x level(3) x oc(256) ==
__global__ __launch_bounds__(256)
void prep_bn_kernel(const float* sg, const float* sbb, const float* smm,
                    const float* svv, const float* sb,
                    const float* eg, const float* ebb, const float* emm,
                    const float* evv, const float* eb,
                    float* __restrict__ scale, float* __restrict__ shift)
{
    int i = blockIdx.x * 256 + threadIdx.x;
    if (i >= 1536) return;
    const int tw = i / 768;
    const int r  = i - tw * 768;          // lvl*256 + oc
    const int oc = r & 255;
    float g, bbv, m, v, cb;
    if (tw == 0) { g = sg[r]; bbv = sbb[r]; m = smm[r]; v = svv[r]; cb = sb[oc]; }
    else         { g = eg[r]; bbv = ebb[r]; m = emm[r]; v = evv[r]; cb = eb[oc]; }
    const float inv = 1.0f / sqrtf(v + 1e-5f);
    const float sc = g * inv;
    scale[i] = sc;
    shift[i] = (cb - m) * sc + bbv;
}

// ===================== zero-fill a f16 buffer (x8 groups) ==================
__global__ __launch_bounds__(256)
void zero16_kernel(f16x8* __restrict__ p, int n8)
{
    const int i = blockIdx.x * 256 + threadIdx.x;
    if (i < n8) p[i] = (f16x8){};
}

// ===== fill fpad16 hi/lo: padded-corner HWC f16 [lvlb][36*36][256] =========
__global__ __launch_bounds__(256)
void fpad16_fill_kernel(const float* __restrict__ feat0,
                        const float* __restrict__ feat1,
                        const float* __restrict__ feat2,
                        f16* __restrict__ xH, f16* __restrict__ xL)
{
    const int h    = blockIdx.x;
    const int lvlb = blockIdx.y;
    const int lvl  = lvlb >> 2, b = lvlb & 3;
    const int logW = 7 - lvl, H = 128 >> lvl;
    if (h >= H) return;                    // lvl2: rows h>=32 stay zero
    const int Wv = (H >= 34) ? 34 : 32;    // valid w count
    const int tid = threadIdx.x;
    const float* f = (lvl == 0) ? feat0 : (lvl == 1 ? feat1 : feat2);

    __shared__ float T[34][257];

    const int wl = tid & 31;
    const int cg = tid >> 5;               // 0..7
#pragma unroll
    for (int cb = 0; cb < 32; cb++) {
        const int c = cb * 8 + cg;
        const float* row = f + (((size_t)(b * C_CH + c)) << (2 * logW))
                             + ((size_t)h << logW);
        T[wl][c] = row[wl];
        if (wl < 2 && (wl + 32) < Wv) T[wl + 32][c] = row[wl + 32];
    }
    __syncthreads();
    const size_t rb = ((size_t)lvlb * 1296 + (size_t)(h + 2) * 36 + 2) * 256 + tid;
    for (int w = 0; w < Wv; w++) {
        const float v = T[w][tid];
        const f16 hh = (f16)v;
        xH[rb + (size_t)w * 256] = hh;
        xL[rb + (size_t)w * 256] = (f16)((v - (float)hh) * 1024.f);
    }
}

// ===== transpose-pad: feat fp32 [4][256][H][W] -> f16 HWC padded interior ==
__global__ __launch_bounds__(256)
void pad_hwc_kernel(const float* __restrict__ feat, f16* __restrict__ xT,
                    int H, int logW)
{
    const int W = 1 << logW;
    const int HW = H << logW;
    const int WP = W + 2, HP = H + 2;
    const int tid = threadIdx.x;
    const int nt  = HW >> 6;
    const int b   = blockIdx.x / nt;
    const int p0  = (blockIdx.x - b * nt) * 64;

    __shared__ f16 T[64][264];

    const int cBase = tid >> 4;
    const int pl4   = (tid & 15) * 4;
#pragma unroll
    for (int it = 0; it < 16; it++) {
        const int c = it * 16 + cBase;
        const float4 v = *(const float4*)(feat + (size_t)(b * C_CH + c) * HW + p0 + pl4);
        T[pl4 + 0][c] = (f16)v.x;
        T[pl4 + 1][c] = (f16)v.y;
        T[pl4 + 2][c] = (f16)v.z;
        T[pl4 + 3][c] = (f16)v.w;
    }
    __syncthreads();
    const int pl = tid >> 2;
    const int c0 = (tid & 3) * 64;
    const int p  = p0 + pl;
    const int h  = p >> logW, w = p & (W - 1);
    f16* dst = xT + ((size_t)(b * HP + h + 1) * WP + (w + 1)) * C_CH + c0;
#pragma unroll
    for (int i = 0; i < 64; i += 8)
        *(f16x8*)(dst + i) = *(const f16x8*)&T[pl][c0 + i];
}

// ============== zero border positions of a padded HWC f16 buffer ===========
__global__ __launch_bounds__(256)
void zero_cl_border_kernel(f16* __restrict__ xT, int H, int W, int n)
{
    const int WP = W + 2, HP = H + 2;
    const int BS = 2 * WP + 2 * H;
    int i = blockIdx.x * 256 + threadIdx.x;
    if (i >= n) return;
    const int ch = (i & 7) * 32;
    const int bc = i >> 3;
    const int b  = bc / BS;
    const int e  = bc - b * BS;
    int padpos;
    if (e < WP)            padpos = e;
    else if (e < 2 * WP)   padpos = (H + 1) * WP + (e - WP);
    else {
        const int e2 = e - 2 * WP;
        padpos = ((e2 >> 1) + 1) * WP + ((e2 & 1) ? (W + 1) : 0);
    }
    f16* dst = xT + ((size_t)b * HP * WP + padpos) * C_CH + ch;
    const f16x8 z = {};
#pragma unroll
    for (int j = 0; j < 32; j += 8) *(f16x8*)(dst + j) = z;
}

// =================== MFMA f16 conv3x3 + BN + ReLU (fast path) ==============
// R13-proven schedule. R16: if emp != nullptr (ent pass), the epilogue
// fuses the ehead dot product (LDS-reduce to emPart[ocTile][4HW]) and the
// conv output is NOT stored (exT eliminated).
__global__ __launch_bounds__(256, 3)
void conv_mfma_kernel(const f16* __restrict__ xT, const f16* __restrict__ wT,
                      const float* __restrict__ scale,
                      const float* __restrict__ shift,
                      f16* __restrict__ y, int H, int logW, int opad,
                      float* __restrict__ emp, const float* __restrict__ ehw)
{
    const int W  = 1 << logW;
    const int WP = W + 2, HP = H + 2;
    const int HW = H << logW;
    const int tid  = threadIdx.x;
    const int wv   = tid >> 6, lane = tid & 63;

    // --- XCD-chunked bijective swizzle (nwg % 8 == 0 for all levels) ---
    const int nwg = gridDim.x;
    const int bid = blockIdx.x;
    const int wg  = (bid & 7) * (nwg >> 3) + (bid >> 3);
    const int ocBase = (wg & 1) * 128;     // oc-tiles of one pos-tile adjacent
    const int pBase  = (wg >> 1) * 128;
    const int b    = pBase / HW;
    const int rem0 = pBase - b * HW;

    // 2 x (A[128][32] + B[128][32]) f16 = 32 KB
    __shared__ f16 sbuf[16384];

    f32x4 acc[4][4];
#pragma unroll
    for (int i = 0; i < 4; i++)
#pragma unroll
        for (int j = 0; j < 4; j++) acc[i][j] = (f32x4){0.f, 0.f, 0.f, 0.f};

    // --- staging: per wave, 2 calls A + 2 calls B, 1KB each (lane*16B) ---
    const int lr = lane >> 2, ls = lane & 3;
    const int r0 = (wv * 2) * 16 + lr;
    const int r1 = (wv * 2 + 1) * 16 + lr;
    const int c0s = (ls ^ ((r0 >> 1) & 3)) * 8;
    const int c1s = (ls ^ ((r1 >> 1) & 3)) * 8;
    const f16* aSrc0 = wT + (size_t)(ocBase + r0) * KTOT + c0s;
    const f16* aSrc1 = wT + (size_t)(ocBase + r1) * KTOT + c1s;
    const int pp0 = rem0 + r0, pp1 = rem0 + r1;
    const f16* bSrc0 = xT + ((size_t)(b * HP + (pp0 >> logW) + 1) * WP
                             + (pp0 & (W - 1)) + 1) * C_CH + c0s;
    const f16* bSrc1 = xT + ((size_t)(b * HP + (pp1 >> logW) + 1) * WP
                             + (pp1 & (W - 1)) + 1) * C_CH + c1s;

    // --- fragment ds_read offsets (f16 units), swizzled cols ---
    const int rw = (wv & 1) * 64;
    const int cw = (wv >> 1) * 64;
    const int lm = lane & 15, lq = lane >> 4;
    int aOff[4], bOff[4];
#pragma unroll
    for (int mi = 0; mi < 4; mi++) {
        const int R = rw + mi * 16 + lm;
        aOff[mi] = R * 32 + ((lq ^ ((R >> 1) & 3)) << 3);
    }
#pragma unroll
    for (int ni = 0; ni < 4; ni++) {
        const int R = cw + ni * 16 + lm;
        bOff[ni] = 4096 + R * 32 + ((lq ^ ((R >> 1) & 3)) << 3);
    }

    auto STAGE = [&](int kn, int nb) {
        const int tap = kn >> 8;
        const int kh  = tap / 3;
        const int kw  = tap - 3 * kh;
        const int tOff = ((kh - 1) * WP + (kw - 1)) * C_CH + (kn & 255);
        f16* lb = &sbuf[nb * 8192 + wv * 1024];          // wave-uniform base
        GLL16(aSrc0 + kn, lb);
        GLL16(aSrc1 + kn, lb + 512);
        GLL16(bSrc0 + tOff, lb + 4096);
        GLL16(bSrc1 + tOff, lb + 4096 + 512);
    };

    STAGE(0, 0);
    __syncthreads();                       // drains vmcnt(0) before s_barrier
    int cur = 0;
    for (int k0 = 0; k0 < KTOT; k0 += 32) {
        if (k0 + 32 < KTOT) STAGE(k0 + 32, cur ^ 1);   // overlap with compute
        const f16* sb = &sbuf[cur * 8192];
        f16x8 af[4], bf[4];
#pragma unroll
        for (int mi = 0; mi < 4; mi++) af[mi] = *(const f16x8*)(sb + aOff[mi]);
#pragma unroll
        for (int ni = 0; ni < 4; ni++) bf[ni] = *(const f16x8*)(sb + bOff[ni]);
#pragma unroll
        for (int mi = 0; mi < 4; mi++)
#pragma unroll
            for (int ni = 0; ni < 4; ni++)
                acc[mi][ni] = __builtin_amdgcn_mfma_f32_16x16x32_f16(
                    af[mi], bf[ni], acc[mi][ni], 0, 0, 0);
        __syncthreads();                   // drain next-tile loads + flip
        cur ^= 1;
    }

    float sc[4][4], sh[4][4];
#pragma unroll
    for (int mi = 0; mi < 4; mi++)
#pragma unroll
        for (int r = 0; r < 4; r++) {
            const int oc = ocBase + rw + mi * 16 + lq * 4 + r;
            sc[mi][r] = scale[oc];
            sh[mi][r] = shift[oc];
        }

    if (emp) {
        // fused ehead: per-thread partial dot over 16 ocs x 4 positions,
        // LDS-reduce 8 contributors per position (exact_full<ent> pattern).
        float pni[4] = {0.f, 0.f, 0.f, 0.f};
#pragma unroll
        for (int mi = 0; mi < 4; mi++)
#pragma unroll
            for (int r = 0; r < 4; r++) {
                const float w = ehw[ocBase + rw + mi * 16 + lq * 4 + r];
#pragma unroll
                for (int ni = 0; ni < 4; ni++) {
                    const float v = fmaxf(
                        fmaf(acc[mi][ni][r], sc[mi][r], sh[mi][r]), 0.f);
                    pni[ni] = fmaf(w, v, pni[ni]);
                }
            }
        float* pa = (float*)sbuf;          // [128][8] floats = 4KB
        const int slot = lq + 4 * (wv & 1);
#pragma unroll
        for (int ni = 0; ni < 4; ni++)
            pa[(cw + ni * 16 + lm) * 8 + slot] = pni[ni];
        __syncthreads();
        if (tid < 128) {
            float s = pa[tid * 8];
#pragma unroll
            for (int j = 1; j < 8; j++) s += pa[tid * 8 + j];
            emp[(size_t)(ocBase >> 7) * (4 * (size_t)HW) + pBase + tid] = s;
        }
        return;
    }

#pragma unroll
    for (int ni = 0; ni < 4; ni++) {
        const int pp = rem0 + cw + ni * 16 + lm;
        size_t dst;
        if (opad) {
            const int h2 = pp >> logW, w2 = pp & (W - 1);
            dst = ((size_t)(b * HP + h2 + 1) * WP + (w2 + 1)) * C_CH;
        } else {
            dst = (size_t)(pBase + cw + ni * 16 + lm) * C_CH;
        }
#pragma unroll
        for (int mi = 0; mi < 4; mi++) {
            const int ocb = ocBase + rw + mi * 16 + lq * 4;
            f16x4 o;
#pragma unroll
            for (int r = 0; r < 4; r++)
                o[r] = (f16)fmaxf(fmaf(acc[mi][ni][r], sc[mi][r], sh[mi][r]), 0.f);
            *(f16x4*)(y + dst + ocb) = o;
        }
    }
}

// ========== em finalize: sum 2 oc-tile partials + bias + sigmoid ===========
__global__ __launch_bounds__(256)
void em_fin_kernel(const float* __restrict__ emp, const float* __restrict__ ehb,
                   float* __restrict__ em, int n)
{
    const int i = blockIdx.x * 256 + threadIdx.x;
    if (i >= n) return;
    const float s = emp[i] + emp[(size_t)n + i] + ehb[0];
    em[i] = 1.0f / (1.0f + expf(-s));
}

// ========== em lvl2 = ape lvl2 slice (same dense grid, exact values) =======
__global__ __launch_bounds__(256)
void em2_copy_kernel(const float* __restrict__ ape, float* __restrict__ em)
{
    const int i = blockIdx.x * 256 + threadIdx.x;   // grid 16 -> 4096
    em[i] = ape[8192 + i];
}

// ====== EXACT paired-f16 MFMA, FULL-K, 64oc x 64pos, fused epilogues =======
// 1D grid, XCD-chunked; wgs&3 = oc quarter (adjacent -> B L2 reuse x4).
// share: 912 blocks; ent: 768 blocks. Dbuf staging (proven schedule).
template<bool IS_SHARE>
__global__ __launch_bounds__(256, 2)
void exact_full_kernel(const f16* __restrict__ xHg, const f16* __restrict__ xLg,
                       const f16* __restrict__ wH, const f16* __restrict__ wL,
                       const float* __restrict__ scale,
                       const float* __restrict__ shift,
                       f16* __restrict__ xOH, f16* __restrict__ xOL,
                       float* __restrict__ apePart, const float* __restrict__ ehw)
{
    constexpr int NTL    = IS_SHARE ? 19 : 16;
    constexpr int IPITCH = IS_SHARE ? 36 : 34;
    constexpr int IPLANE = IS_SHARE ? 1296 : 1156;

    const int tid  = threadIdx.x;
    const int wv   = tid >> 6, lane = tid & 63;

    // --- XCD-chunked bijective swizzle; oc-quarters adjacent ---
    const int nwg = gridDim.x;             // 912 or 768, % 8 == 0
    const int bid = blockIdx.x;
    const int wgs = (bid & 7) * (nwg >> 3) + (bid >> 3);
    const int ocq = wgs & 3;
    const int ti  = wgs >> 2;
    const int lvlb = ti / NTL;
    const int tile = ti - lvlb * NTL;
    const int posBase = tile * 64;
    const int ocBase  = ocq * 64;
    const int lvl  = lvlb >> 2;

    // 2 x (AsH|AsL|BsH|BsL each [64][32]) = 32 KB; epilogue reuses region
    __shared__ f16 sbuf[16384];

    f32x4 accH[2][2], accX[2][2];
#pragma unroll
    for (int i = 0; i < 2; i++)
#pragma unroll
        for (int j = 0; j < 2; j++) {
            accH[i][j] = (f32x4){0.f, 0.f, 0.f, 0.f};
            accX[i][j] = (f32x4){0.f, 0.f, 0.f, 0.f};
        }

    // --- staging: per wave 4 GLL16 (A-H, A-L, B-H, B-L), rows wv*16..+15 ---
    const int lr = lane >> 2, ls = lane & 3;
    const int rA = wv * 16 + lr;                   // 0..63
    const int cAs = (ls ^ ((rA >> 1) & 3)) * 8;    // pre-swizzled col
    const f16* aSrcH = wH + (size_t)(ocBase + rA) * KTOT + cAs;
    const f16* aSrcL = wL + (size_t)(ocBase + rA) * KTOT + cAs;

    int n = posBase + rA;
    if (IS_SHARE && n > 1155) n = 1155;            // tail tile clamp (masked)
    int po;
    if (IS_SHARE) { const int ph = n / 34; po = ph * 36 + (n - ph * 34); }
    else          { po = (n >> 5) * 34 + (n & 31); }
    const f16* bSrcH = xHg + ((size_t)lvlb * IPLANE + po) * 256 + cAs;
    const f16* bSrcL = xLg + ((size_t)lvlb * IPLANE + po) * 256 + cAs;

    // --- fragment ds_read offsets (f16 units), swizzled cols ---
    const int rw = (wv & 1) * 32;                  // oc within 64
    const int cw = (wv >> 1) * 32;                 // pos within 64
    const int lm = lane & 15, lq = lane >> 4;
    int aOff[2], bOff[2];
#pragma unroll
    for (int mi = 0; mi < 2; mi++) {
        const int R = rw + mi * 16 + lm;
        aOff[mi] = R * 32 + ((lq ^ ((R >> 1) & 3)) << 3);
    }
#pragma unroll
    for (int ni = 0; ni < 2; ni++) {
        const int R = cw + ni * 16 + lm;
        bOff[ni] = R * 32 + ((lq ^ ((R >> 1) & 3)) << 3);
    }

    auto STAGE = [&](int kn, int nb) {
        const int tap = kn >> 8;
        const int th  = tap / 3;
        const int tOff = (th * IPITCH + (tap - 3 * th)) * 256 + (kn & 255);
        f16* lb = &sbuf[nb * 8192 + wv * 512];     // wave-uniform bases
        GLL16(aSrcH + kn, lb);
        GLL16(aSrcL + kn, lb + 2048);
        GLL16(bSrcH + tOff, lb + 4096);
        GLL16(bSrcL + tOff, lb + 6144);
    };

    STAGE(0, 0);
    __syncthreads();                       // drains vmcnt(0): tile 0 landed
    int cur = 0;
    for (int ko = 0; ko < KTOT; ko += 32) {
        if (ko + 32 < KTOT) STAGE(ko + 32, cur ^ 1);   // overlap with compute
        const f16* sb = &sbuf[cur * 8192];
        f16x8 aH[2], aL[2];
#pragma unroll
        for (int mi = 0; mi < 2; mi++) {
            aH[mi] = *(const f16x8*)(sb + aOff[mi]);
            aL[mi] = *(const f16x8*)(sb + 2048 + aOff[mi]);
        }
#pragma unroll
        for (int ni = 0; ni < 2; ni++) {
            const f16x8 bh = *(const f16x8*)(sb + 4096 + bOff[ni]);
            const f16x8 bl = *(const f16x8*)(sb + 6144 + bOff[ni]);
#pragma unroll
            for (int mi = 0; mi < 2; mi++)
                accH[mi][ni] = __builtin_amdgcn_mfma_f32_16x16x32_f16(
                    aH[mi], bh, accH[mi][ni], 0, 0, 0);
#pragma unroll
            for (int mi = 0; mi < 2; mi++)
                accX[mi][ni] = __builtin_amdgcn_mfma_f32_16x16x32_f16(
                    aH[mi], bl, accX[mi][ni], 0, 0, 0);
#pragma unroll
            for (int mi = 0; mi < 2; mi++)
                accX[mi][ni] = __builtin_amdgcn_mfma_f32_16x16x32_f16(
                    aL[mi], bh, accX[mi][ni], 0, 0, 0);
        }
        __syncthreads();                   // drain next-tile loads + flip
        cur ^= 1;
    }

    if constexpr (IS_SHARE) {
        // BN+ReLU+mask; stage hi/lo into LDS transpose buf, stride 72 f16.
        // (xsp fp32 store deleted in R16 -- dead since pat_mfma reads H/L.)
#pragma unroll
        for (int mi = 0; mi < 2; mi++)
#pragma unroll
            for (int r = 0; r < 4; r++) {
                const int chl = rw + mi * 16 + lq * 4 + r;    // 0..63
                const int oc  = ocBase + chl;
                const float sc = scale[lvl * 256 + oc];
                const float sh = shift[lvl * 256 + oc];
#pragma unroll
                for (int ni = 0; ni < 2; ni++) {
                    const int pl  = cw + ni * 16 + lm;        // 0..63
                    const int nn  = posBase + pl;
                    const float val = accH[mi][ni][r]
                                    + accX[mi][ni][r] * (1.0f / 1024.0f);
                    const int ph = nn / 34;
                    const int pw = nn - ph * 34;
                    const bool valid = (nn < 1156) && (ph >= 1) && (pw >= 1) &&
                                       (lvl < 2 || (ph <= 32 && pw <= 32));
                    const float o = valid ? fmaxf(fmaf(val, sc, sh), 0.f) : 0.f;
                    const f16 h = (f16)o;
                    sbuf[pl * 72 + chl]        = h;
                    sbuf[4608 + pl * 72 + chl] = (f16)((o - (float)h) * 1024.f);
                }
            }
        __syncthreads();
        const int p  = tid >> 2;
        const int cg = (tid & 3) * 16;
        const int n2 = posBase + p;
        if (n2 < 1156) {
            const size_t gb = ((size_t)lvlb * 1156 + n2) * 256 + ocBase + cg;
            *(f16x8*)(xOH + gb)     = *(const f16x8*)(sbuf + p * 72 + cg);
            *(f16x8*)(xOH + gb + 8) = *(const f16x8*)(sbuf + p * 72 + cg + 8);
            *(f16x8*)(xOL + gb)     = *(const f16x8*)(sbuf + 4608 + p * 72 + cg);
            *(f16x8*)(xOL + gb + 8) = *(const f16x8*)(sbuf + 4608 + p * 72 + cg + 8);
        }
    } else {
        // BN+ReLU; ehead contraction over this block's 64-oc slice
        float* pa = (float*)sbuf;          // [64 cells][8 contributors]
        float pni[2] = {0.f, 0.f};
#pragma unroll
        for (int mi = 0; mi < 2; mi++)
#pragma unroll
            for (int r = 0; r < 4; r++) {
                const int oc = ocBase + rw + mi * 16 + lq * 4 + r;
                const float sc = scale[768 + lvl * 256 + oc];
                const float sh = shift[768 + lvl * 256 + oc];
                const float w  = ehw[oc];
#pragma unroll
                for (int ni = 0; ni < 2; ni++) {
                    const float val = accH[mi][ni][r]
                                    + accX[mi][ni][r] * (1.0f / 1024.0f);
                    pni[ni] = fmaf(w, fmaxf(fmaf(val, sc, sh), 0.f), pni[ni]);
                }
            }
        const int slot = lq + 4 * (wv & 1);
#pragma unroll
        for (int ni = 0; ni < 2; ni++)
            pa[(cw + ni * 16 + lm) * 8 + slot] = pni[ni];
        __syncthreads();
        if (tid < 64) {
            float s = pa[tid * 8];
#pragma unroll
            for (int j = 1; j < 8; j++) s += pa[tid * 8 + j];
            apePart[(size_t)ocq * 12288 + lvlb * 1024 + posBase + tid] = s;
        }
    }
}

// ======= ape finalize: sum 4 oc-quarter partials + bias + sigmoid ==========
__global__ __launch_bounds__(256)
void ape_fin_kernel(const float* __restrict__ apePart,
                    const float* __restrict__ ehb, float* __restrict__ ape)
{
    const int i = blockIdx.x * 256 + threadIdx.x;
    if (i >= 12288) return;
    float s = apePart[i];
    s += apePart[12288 + i];
    s += apePart[24576 + i];
    s += apePart[36864 + i];
    ape[i] = 1.0f / (1.0f + expf(-(s + ehb[0])));
}

// ===================== top-k, all levels (grid 12) =========================
__global__ __launch_bounds__(1024)
void topk_all_kernel(const float* __restrict__ ape, const int* __restrict__ coords,
                     int* __restrict__ xy_int, float* __restrict__ out,
                     int xo0, int xo1, int xo2)
{
    const int lvl = blockIdx.x >> 2;
    const int b   = blockIdx.x & 3;
    const int nk  = 512 >> lvl;
    const int tid = threadIdx.x;
    __shared__ unsigned long long keys[1024];

    const int rr = coords[tid] & 31;
    const int cc0 = coords[1024 + tid] & 31;
    const float v = ape[lvl * 4096 + (b << 10) + (rr << 5) + cc0];
    unsigned u = __float_as_uint(v);
    unsigned mono = (u & 0x80000000u) ? ~u : (u | 0x80000000u);
    keys[tid] = (((unsigned long long)(~mono)) << 32) | (unsigned)tid;
    __syncthreads();

    for (int k = 2; k <= 1024; k <<= 1) {
        for (int j = k >> 1; j > 0; j >>= 1) {
            const int ixj = tid ^ j;
            if (ixj > tid) {
                const bool up = ((tid & k) == 0);
                const unsigned long long a = keys[tid], c = keys[ixj];
                if ((a > c) == up) { keys[tid] = c; keys[ixj] = a; }
            }
            __syncthreads();
        }
    }

    if (tid < nk) {
        const int i  = (int)(keys[tid] & 0x3FFu);
        const int r  = coords[i] & 31;
        const int c  = coords[1024 + i] & 31;
        const int intOff = 8192 - (8192 >> lvl);
        const int o  = intOff + (b * nk + tid) * 2;
        xy_int[o]     = r;
        xy_int[o + 1] = c;
        const int xo = (lvl == 0) ? xo0 : (lvl == 1 ? xo1 : xo2);
        out[xo + (b * nk + tid) * 2]     = (float)r;
        out[xo + (b * nk + tid) * 2 + 1] = (float)c;
    }
}

// ====== pat conv at top-k: paired-f16 MFMA, 32pos x 64oc, split-K x2 =======
__global__ __launch_bounds__(256, 2)
void pat_mfma_kernel(const f16* __restrict__ xHg, const f16* __restrict__ xLg,
                     const f16* __restrict__ wH, const f16* __restrict__ wL,
                     const int* __restrict__ xy_int,
                     float* __restrict__ part)
{
    const int tid = threadIdx.x;
    const int wv  = tid >> 6, lane = tid & 63;
    const int nwg = gridDim.x;             // 896
    const int bid = blockIdx.x;
    const int wgs = (bid & 7) * (nwg >> 3) + (bid >> 3);
    const int z   = wgs & 1;
    const int ocq = (wgs >> 1) & 3;
    const int ti  = wgs >> 3;              // 0..111
    int lvl, pL;
    if (ti < 64)      { lvl = 0; pL = ti * 32; }
    else if (ti < 96) { lvl = 1; pL = (ti - 64) * 32; }
    else              { lvl = 2; pL = (ti - 96) * 32; }
    const int nk   = 512 >> lvl;
    const int bb   = pL / nk;
    const int lvlb = lvl * 4 + bb;
    const int intOff   = 8192 - (8192 >> lvl);
    const int posStart = 4096 - (4096 >> lvl);
    const int ocBase = ocq * 64;
    const int kStart = z * 1152;

    // 2 x (AH[64][32] | AL[64][32] | BH[32][32] | BL[32][32]) = 24 KB
    __shared__ f16 sbuf[12288];
    __shared__ int pofs[32];

    if (tid < 32) {
        const int n = pL + tid;
        const int r = xy_int[intOff + n * 2]     & 31;
        const int c = xy_int[intOff + n * 2 + 1] & 31;
        pofs[tid] = r * 34 + c;            // corner of 3x3 window (padded)
    }
    __syncthreads();

    f32x4 accH[2], accX[2];
#pragma unroll
    for (int i = 0; i < 2; i++) {
        accH[i] = (f32x4){0.f, 0.f, 0.f, 0.f};
        accX[i] = (f32x4){0.f, 0.f, 0.f, 0.f};
    }

    const int lr = lane >> 2, ls = lane & 3;
    // A: wave wv stages oc rows wv*16..+15 (hi and lo)
    const int rA  = wv * 16 + lr;
    const int cAs = (ls ^ ((rA >> 1) & 3)) * 8;
    const f16* aSrcH = wH + (size_t)(ocBase + rA) * KTOT + kStart + cAs;
    const f16* aSrcL = wL + (size_t)(ocBase + rA) * KTOT + kStart + cAs;
    // B: waves 0,1 stage B-H rows 0-15/16-31; waves 2,3 stage B-L same rows
    const int rB  = (wv & 1) * 16 + lr;    // 0..31
    const int cBs = (ls ^ ((rB >> 1) & 3)) * 8;
    const f16* bBase = (wv < 2) ? xHg : xLg;
    const f16* bSrc = bBase + ((size_t)lvlb * 1156 + pofs[rB]) * 256 + cBs;
    const int bDst = ((wv < 2) ? 4096 : 5120) + (wv & 1) * 512;

    // frag offsets
    const int rw = (wv & 1) * 32;          // oc within 64
    const int pw = (wv >> 1) * 16;         // pos within 32
    const int lm = lane & 15, lq = lane >> 4;
    int aOff[2];
#pragma unroll
    for (int mi = 0; mi < 2; mi++) {
        const int R = rw + mi * 16 + lm;
        aOff[mi] = R * 32 + ((lq ^ ((R >> 1) & 3)) << 3);
    }
    const int Rb = pw + lm;
    const int bOff = 4096 + Rb * 32 + ((lq ^ ((Rb >> 1) & 3)) << 3);

    auto STAGE = [&](int kRel, int nb) {
        const int kAbs = kStart + kRel;
        const int tap  = kAbs >> 8;
        const int th   = tap / 3;
        const int tOff = (th * 34 + (tap - 3 * th)) * 256 + (kAbs & 255);
        f16* base = &sbuf[nb * 6144];
        GLL16(aSrcH + kRel, base + wv * 512);            // A-H
        GLL16(aSrcL + kRel, base + 2048 + wv * 512);     // A-L
        GLL16(bSrc + tOff,  base + bDst);                // B (H or L half)
    };

    STAGE(0, 0);
    __syncthreads();                       // drains vmcnt(0): tile 0 landed
    int cur = 0;
    for (int ko = 0; ko < 1152; ko += 32) {
        if (ko + 32 < 1152) STAGE(ko + 32, cur ^ 1);   // overlap with compute
        const f16* sb = &sbuf[cur * 6144];
        f16x8 aH[2], aL[2];
#pragma unroll
        for (int mi = 0; mi < 2; mi++) {
            aH[mi] = *(const f16x8*)(sb + aOff[mi]);
            aL[mi] = *(const f16x8*)(sb + 2048 + aOff[mi]);
        }
        const f16x8 bh = *(const f16x8*)(sb + bOff);
        const f16x8 bl = *(const f16x8*)(sb + 1024 + bOff);
#pragma unroll
        for (int mi = 0; mi < 2; mi++)
            accH[mi] = __builtin_amdgcn_mfma_f32_16x16x32_f16(
                aH[mi], bh, accH[mi], 0, 0, 0);
#pragma unroll
        for (int mi = 0; mi < 2; mi++)
            accX[mi] = __builtin_amdgcn_mfma_f32_16x16x32_f16(
                aH[mi], bl, accX[mi], 0, 0, 0);
#pragma unroll
        for (int mi = 0; mi < 2; mi++)
            accX[mi] = __builtin_amdgcn_mfma_f32_16x16x32_f16(
                aL[mi], bh, accX[mi], 0, 0, 0);
        __syncthreads();                   // drain next-tile loads + flip
        cur ^= 1;
    }

    // raw conv partials, [pos][256] fp32; BN applied in pat_reduce
    float* op = part + (size_t)z * PAT_N
              + (size_t)(posStart + pL + pw + lm) * C_CH + ocBase;
#pragma unroll
    for (int mi = 0; mi < 2; mi++)
#pragma unroll
        for (int r = 0; r < 4; r++)
            op[rw + mi * 16 + lq * 4 + r] =
                accH[mi][r] + accX[mi][r] * (1.0f / 1024.0f);
}

// ===== pat split-K x2 reduce (fixed order) + BN + ReLU -> af [3584][256] ===
__global__ __launch_bounds__(256)
void pat_reduce_kernel(const float* __restrict__ part,
                       const float* __restrict__ cb,
                       const float* __restrict__ bng, const float* __restrict__ bnb,
                       const float* __restrict__ bnm, const float* __restrict__ bnv,
                       float* __restrict__ af)
{
    const int i4 = (blockIdx.x * 256 + threadIdx.x) * 4;
    if (i4 >= PAT_N) return;
    const int pos = i4 >> 8;
    const int oc0 = i4 & 255;
    const int lvl = (pos < 2048) ? 0 : (pos < 3072 ? 1 : 2);
    float4 s = *(const float4*)(part + i4);
    {
        const float4 t = *(const float4*)(part + (size_t)PAT_N + i4);
        s.x += t.x; s.y += t.y; s.z += t.z; s.w += t.w;
    }
    const float4 g  = *(const float4*)(bng + lvl * 256 + oc0);
    const float4 bb = *(const float4*)(bnb + lvl * 256 + oc0);
    const float4 m  = *(const float4*)(bnm + lvl * 256 + oc0);
    const float4 v  = *(const float4*)(bnv + lvl * 256 + oc0);
    const float4 cb4 = *(const float4*)(cb + oc0);
    float4 o;
    {
        float inv = 1.0f / sqrtf(v.x + 1e-5f); float sc = g.x * inv;
        o.x = fmaxf(fmaf(s.x, sc, (cb4.x - m.x) * sc + bb.x), 0.f);
        inv = 1.0f / sqrtf(v.y + 1e-5f); sc = g.y * inv;
        o.y = fmaxf(fmaf(s.y, sc, (cb4.y - m.y) * sc + bb.y), 0.f);
        inv = 1.0f / sqrtf(v.z + 1e-5f); sc = g.z * inv;
        o.z = fmaxf(fmaf(s.z, sc, (cb4.z - m.z) * sc + bb.z), 0.f);
        inv = 1.0f / sqrtf(v.w + 1e-5f); sc = g.w * inv;
        o.w = fmaxf(fmaf(s.w, sc, (cb4.w - m.w) * sc + bb.w), 0.f);
    }
    *(float4*)(af + i4) = o;
}

// ============ head + final boxes, all levels (grid 3584) ===================
__global__ __launch_bounds__(256)
void head_final_all_kernel(const float* __restrict__ af, const float* __restrict__ hw,
                           const float* __restrict__ hb, const int* __restrict__ xy_int,
                           float* __restrict__ out, int fo0, int fo1, int fo2)
{
    const int pos = blockIdx.x;
    const int lvl = (pos < 2048) ? 0 : (pos < 3072 ? 1 : 2);
    const int local = pos - (4096 - (4096 >> lvl));
    const int intOff = 8192 - (8192 >> lvl);
    const int fo = (lvl == 0) ? fo0 : (lvl == 1 ? fo1 : fo2);
    const int tid  = threadIdx.x;
    const int j4   = tid >> 6;
    const int lane = tid & 63;
    const float* a = af + (size_t)pos * C_CH;
    const float* w = hw + j4 * C_CH;
    float sum = 0.f;
#pragma unroll
    for (int i = 0; i < 4; i++)
        sum = fmaf(a[lane + 64 * i], w[lane + 64 * i], sum);
#pragma unroll
    for (int off = 32; off > 0; off >>= 1) sum += __shfl_down(sum, off);
    if (lane == 0) {
        const float pc = 1.0f / (1.0f + expf(-(sum + hb[j4])));
        const float ax = (float)xy_int[intOff + local * 2];
        const float ay = (float)xy_int[intOff + local * 2 + 1];
        float val;
        if      (j4 == 0) val = ax - 16.0f * pc;
        else if (j4 == 1) val = ay - 16.0f * pc;
        else if (j4 == 2) val = ax + 16.0f * pc;
        else              val = ay + 16.0f * pc;
        out[fo + local * 4 + j4] = val;
    }
}

// ============================== launcher ===================================
extern "C" void kernel_launch(void* const* d_in, const int* in_sizes, int n_in,
                              void* d_out, int out_size, void* d_ws, size_t ws_size,
                              hipStream_t stream) {
    const float* feat[3] = {(const float*)d_in[0], (const float*)d_in[1],
                            (const float*)d_in[2]};
    const int*   coords  = (const int*)d_in[3];
    const float* sw  = (const float*)d_in[4];
    const float* sb  = (const float*)d_in[5];
    const float* sg  = (const float*)d_in[6];
    const float* sbb = (const float*)d_in[7];
    const float* smm = (const float*)d_in[8];
    const float* svv = (const float*)d_in[9];
    const float* ew  = (const float*)d_in[10];
    const float* eb  = (const float*)d_in[11];
    const float* eg  = (const float*)d_in[12];
    const float* ebb = (const float*)d_in[13];
    const float* emm = (const float*)d_in[14];
    const float* evv = (const float*)d_in[15];
    const float* pw  = (const float*)d_in[16];
    const float* pb  = (const float*)d_in[17];
    const float* pg  = (const float*)d_in[18];
    const float* pbb = (const float*)d_in[19];
    const float* pmm = (const float*)d_in[20];
    const float* pvv = (const float*)d_in[21];
    const float* ehw = (const float*)d_in[22];
    const float* ehb = (const float*)d_in[23];
    const float* hww = (const float*)d_in[24];
    const float* hbb = (const float*)d_in[25];

    float* out = (float*)d_out;
    char*  ws  = (char*)d_ws;

    // ---- workspace layout (bytes from ws) ----
    f16*   wTs    = (f16*)(ws);                         // 0        (1.18MB)
    f16*   wTe    = (f16*)(ws + 1310720);
    f16*   wTsL   = (f16*)(ws + 2621440);
    f16*   wTeL   = (f16*)(ws + 3932160);
    float* scales = (float*)(ws + 5242880);
    float* shifts = (float*)(ws + 5251072);
    // exact path
    f16*   fpadH  = (f16*)(ws + 6291456);               // 6MB   (7.96MB)
    f16*   fpadL  = (f16*)(ws + 14254080);              // contiguous after H
    float* patPart= (float*)(ws + 6291456);             // reuses fpad16 (dead)
    float* emPart = (float*)(ws + 6291456);             // fast path: dead region
    float* af     = (float*)(ws + 23068672);            // 22MB  (3.5MB)
    f16*   wTp    = (f16*)(ws + 27262976);              // exact-path-only; the
    f16*   wTpL   = (f16*)(ws + 28573696);              // fast path clobbers
    f16*   xspH   = (f16*)(ws + 90177536);              // 86MB  (6.8MB)
    f16*   xspL   = (f16*)(ws + 97280000);
    float* ape    = (float*)(ws + 119537664);           // 114MB (48KB)
    int*   xy_int = (int*)  (ws + 119603200);           // (32KB)
    float* apePart= (float*)(ws + 119668736);           // (192KB)
    // fast path (runs after exact path; reuses dead exact regions)
    f16*   featT  = (f16*)(ws + 27262976);              // 26MB (34.6MB, lvl0)
    f16*   xsT    = (f16*)(ws + 65011712);              // 62MB (34.6MB) disjoint

    const int Hs[3]    = {128, 64, 32};
    const int logWs[3] = {7, 6, 5};
    const int nks[3]   = {512, 256, 128};

    size_t off = 0;
    size_t emOff[3], finOff[3], xyOff[3];
    for (int l = 0; l < 3; l++) {
        const int HW = Hs[l] * Hs[l];
        emOff[l]  = off; off += (size_t)4 * HW;
        finOff[l] = off; off += (size_t)4 * nks[l] * 4;
        xyOff[l]  = off; off += (size_t)4 * nks[l] * 2;
    }

    // -------- prep --------
    prep_weights_kernel<<<(C_CH * KTOT + 255) / 256, 256, 0, stream>>>(
        sw, ew, pw, wTs, wTe, wTsL, wTeL, wTp, wTpL, C_CH * KTOT);
    prep_bn_kernel<<<6, 256, 0, stream>>>(sg, sbb, smm, svv, sb,
                                          eg, ebb, emm, evv, eb, scales, shifts);

    // -------- exact path --------
    zero16_kernel<<<(995328 + 255) / 256, 256, 0, stream>>>((f16x8*)fpadH, 995328);
    fpad16_fill_kernel<<<dim3(34, 12), 256, 0, stream>>>(
        feat[0], feat[1], feat[2], fpadH, fpadL);
    exact_full_kernel<true><<<912, 256, 0, stream>>>(
        fpadH, fpadL, wTs, wTsL, scales, shifts, xspH, xspL,
        nullptr, nullptr);
    exact_full_kernel<false><<<768, 256, 0, stream>>>(
        xspH, xspL, wTe, wTeL, scales, shifts, nullptr, nullptr,
        apePart, ehw);
    ape_fin_kernel<<<48, 256, 0, stream>>>(apePart, ehb, ape);
    topk_all_kernel<<<12, 1024, 0, stream>>>(
        ape, coords, xy_int, out, (int)xyOff[0], (int)xyOff[1], (int)xyOff[2]);
    pat_mfma_kernel<<<896, 256, 0, stream>>>(
        xspH, xspL, wTp, wTpL, xy_int, patPart);
    pat_reduce_kernel<<<(PAT_N / 1024), 256, 0, stream>>>(
        patPart, pb, pg, pbb, pmm, pvv, af);
    head_final_all_kernel<<<PAT_POS, 256, 0, stream>>>(
        af, hww, hbb, xy_int, out, (int)finOff[0], (int)finOff[1], (int)finOff[2]);

    // -------- fast path (f16 MFMA), lvl 0..1 only --------
    // (lvl2 em == ape lvl2 slice exactly: same dense grid, exact math.)
    for (int lvl = 0; lvl < 2; lvl++) {
        const int H = Hs[lvl], logW = logWs[lvl];
        const int W = H;
        const int HW = H << logW;
        const int WP = W + 2;
        const int nbord = 4 * (2 * WP + 2 * H) * 8;

        pad_hwc_kernel<<<4 * HW / 64, 256, 0, stream>>>(feat[lvl], featT, H, logW);
        zero_cl_border_kernel<<<(nbord + 255) / 256, 256, 0, stream>>>(
            featT, H, W, nbord);
        zero_cl_border_kernel<<<(nbord + 255) / 256, 256, 0, stream>>>(
            xsT, H, W, nbord);
        dim3 gconv((4 * HW / 128) * 2);     // 1D: wg&1 = oc tile, wg>>1 = pos
        conv_mfma_kernel<<<gconv, 256, 0, stream>>>(
            featT, wTs, scales + lvl * 256, shifts + lvl * 256, xsT, H, logW, 1,
            nullptr, nullptr);
        conv_mfma_kernel<<<gconv, 256, 0, stream>>>(
            xsT, wTe, scales + 768 + lvl * 256, shifts + 768 + lvl * 256,
            nullptr, H, logW, 0, emPart, ehw);
        em_fin_kernel<<<(4 * HW + 255) / 256, 256, 0, stream>>>(
            emPart, ehb, out + emOff[lvl], 4 * HW);
    }
    em2_copy_kernel<<<16, 256, 0, stream>>>(ape, out + emOff[2]);
}

// Round 12
// 675.048 us; speedup vs baseline: 1.4010x; 1.0108x over previous
//
#include <hip/hip_runtime.h>
#include <cstdint>
#include <cstddef>

// ---------------------------------------------------------------------------
// PatchModule R17 (resubmit — first R17 bench was an infra failure:
// "container failed twice", no pytest/counter output; launch-bounds change
// audited for resource legality — conv 32KBx4=128KB LDS, VGPR 56<=128;
// exact_full 48<=128; pat 24KBx4=97KB — and resubmitted byte-identical,
// same precedent as R13's clean resubmit).
// R17 — occupancy floors raised (the only change vs R16-proven):
//   conv_mfma   __launch_bounds__(256,3) -> (256,4)  [grid lvl0 = 4/CU]
//   exact_full  __launch_bounds__(256,2) -> (256,4)  [grid 3.6/CU, LDS 32KB]
//   pat_mfma    __launch_bounds__(256,2) -> (256,4)  [grid 3.5/CU, LDS 24KB]
//   Rationale: conv lvl0 counters show Occupancy 35% == the (256,3) floor
//   exactly; VGPR 56 and LDS 32KB permit 4 blocks/CU. m114: cross-block
//   wave overlap hides the per-block __syncthreads vmcnt(0) drain -- more
//   resident blocks hide more of the ~20% structural stall. Pure scheduling
//   capacity change: data, sync structure, MFMA order all bit-identical.
// Everything else: R16-proven, byte-identical.
// All gathered indices masked &31 (rocprof replay poison safety).
// ---------------------------------------------------------------------------

typedef _Float16 f16;
typedef _Float16 f16x4 __attribute__((ext_vector_type(4)));
typedef _Float16 f16x8 __attribute__((ext_vector_type(8)));
typedef float    f32x4 __attribute__((ext_vector_type(4)));

constexpr int C_CH = 256;
constexpr int KTOT = 2304;
constexpr int PAT_POS = 3584;              // 2048+1024+512
constexpr int PAT_N   = PAT_POS * C_CH;

// async global->LDS, 16B per lane, dest = wave-uniform base + lane*16
#define GLL16(g, l) __builtin_amdgcn_global_load_lds(                        \
    (const __attribute__((address_space(1))) unsigned int*)(g),              \
    (__attribute__((address_space(3))) unsigned int*)(l), 16, 0, 0)

// == prep: weights fp32 [oc][ic*9+tap] -> f16 hi/lo [oc][tap*256+ic] x3 =====
__global__ __launch_bounds__(256)
void prep_weights_kernel(const float* __restrict__ sw, const float* __restrict__ ew,
                         const float* __restrict__ pw,
                         f16* __restrict__ wTs, f16* __restrict__ wTe,
                         f16* __restrict__ wTsL, f16* __restrict__ wTeL,
                         f16* __restrict__ wTp, f16* __restrict__ wTpL, int n)
{
    int i = blockIdx.x * 256 + threadIdx.x;
    if (i >= n) return;
    const int oc = i / KTOT;
    const int kp = i - oc * KTOT;
    const int tap = kp >> 8;
    const int ic  = kp & 255;
    const int src = oc * KTOT + ic * 9 + tap;
    const float vs = sw[src];
    const f16 hs = (f16)vs;
    wTs[i]  = hs;
    wTsL[i] = (f16)((vs - (float)hs) * 1024.f);
    const float ve = ew[src];
    const f16 he = (f16)ve;
    wTe[i]  = he;
    wTeL[i] = (f16)((ve - (float)he) * 1024.f);
    const float vp = pw[src];
    const f16 hp = (f16)vp;
    wTp[i]  = hp;
    wTpL[i] = (f16)((vp - (float)hp) * 1024.f);
}

// ================= prep: BN scale/shift per tower(2) x level(3) x oc(256) ==
__global__ __launch_bounds__(256)
void prep_bn_kernel(const float* sg, const float* sbb, const float* smm,
                    const float* svv, const float* sb,
                    const float* eg, const float* ebb, const float* emm,
                    const float* evv, const float* eb,
                    float* __restrict__ scale, float* __restrict__ shift)
{
    int i = blockIdx.x * 256 + threadIdx.x;
    if (i >= 1536) return;
    const int tw = i / 768;
    const int r  = i - tw * 768;          // lvl*256 + oc
    const int oc = r & 255;
    float g, bbv, m, v, cb;
    if (tw == 0) { g = sg[r]; bbv = sbb[r]; m = smm[r]; v = svv[r]; cb = sb[oc]; }
    else         { g = eg[r]; bbv = ebb[r]; m = emm[r]; v = evv[r]; cb = eb[oc]; }
    const float inv = 1.0f / sqrtf(v + 1e-5f);
    const float sc = g * inv;
    scale[i] = sc;
    shift[i] = (cb - m) * sc + bbv;
}

// ===================== zero-fill a f16 buffer (x8 groups) ==================
__global__ __launch_bounds__(256)
void zero16_kernel(f16x8* __restrict__ p, int n8)
{
    const int i = blockIdx.x * 256 + threadIdx.x;
    if (i < n8) p[i] = (f16x8){};
}

// ===== fill fpad16 hi/lo: padded-corner HWC f16 [lvlb][36*36][256] =========
__global__ __launch_bounds__(256)
void fpad16_fill_kernel(const float* __restrict__ feat0,
                        const float* __restrict__ feat1,
                        const float* __restrict__ feat2,
                        f16* __restrict__ xH, f16* __restrict__ xL)
{
    const int h    = blockIdx.x;
    const int lvlb = blockIdx.y;
    const int lvl  = lvlb >> 2, b = lvlb & 3;
    const int logW = 7 - lvl, H = 128 >> lvl;
    if (h >= H) return;                    // lvl2: rows h>=32 stay zero
    const int Wv = (H >= 34) ? 34 : 32;    // valid w count
    const int tid = threadIdx.x;
    const float* f = (lvl == 0) ? feat0 : (lvl == 1 ? feat1 : feat2);

    __shared__ float T[34][257];

    const int wl = tid & 31;
    const int cg = tid >> 5;               // 0..7
#pragma unroll
    for (int cb = 0; cb < 32; cb++) {
        const int c = cb * 8 + cg;
        const float* row = f + (((size_t)(b * C_CH + c)) << (2 * logW))
                             + ((size_t)h << logW);
        T[wl][c] = row[wl];
        if (wl < 2 && (wl + 32) < Wv) T[wl + 32][c] = row[wl + 32];
    }
    __syncthreads();
    const size_t rb = ((size_t)lvlb * 1296 + (size_t)(h + 2) * 36 + 2) * 256 + tid;
    for (int w = 0; w < Wv; w++) {
        const float v = T[w][tid];
        const f16 hh = (f16)v;
        xH[rb + (size_t)w * 256] = hh;
        xL[rb + (size_t)w * 256] = (f16)((v - (float)hh) * 1024.f);
    }
}

// ===== transpose-pad: feat fp32 [4][256][H][W] -> f16 HWC padded interior ==
__global__ __launch_bounds__(256)
void pad_hwc_kernel(const float* __restrict__ feat, f16* __restrict__ xT,
                    int H, int logW)
{
    const int W = 1 << logW;
    const int HW = H << logW;
    const int WP = W + 2, HP = H + 2;
    const int tid = threadIdx.x;
    const int nt  = HW >> 6;
    const int b   = blockIdx.x / nt;
    const int p0  = (blockIdx.x - b * nt) * 64;

    __shared__ f16 T[64][264];

    const int cBase = tid >> 4;
    const int pl4   = (tid & 15) * 4;
#pragma unroll
    for (int it = 0; it < 16; it++) {
        const int c = it * 16 + cBase;
        const float4 v = *(const float4*)(feat + (size_t)(b * C_CH + c) * HW + p0 + pl4);
        T[pl4 + 0][c] = (f16)v.x;
        T[pl4 + 1][c] = (f16)v.y;
        T[pl4 + 2][c] = (f16)v.z;
        T[pl4 + 3][c] = (f16)v.w;
    }
    __syncthreads();
    const int pl = tid >> 2;
    const int c0 = (tid & 3) * 64;
    const int p  = p0 + pl;
    const int h  = p >> logW, w = p & (W - 1);
    f16* dst = xT + ((size_t)(b * HP + h + 1) * WP + (w + 1)) * C_CH + c0;
#pragma unroll
    for (int i = 0; i < 64; i += 8)
        *(f16x8*)(dst + i) = *(const f16x8*)&T[pl][c0 + i];
}

// ============== zero border positions of a padded HWC f16 buffer ===========
__global__ __launch_bounds__(256)
void zero_cl_border_kernel(f16* __restrict__ xT, int H, int W, int n)
{
    const int WP = W + 2, HP = H + 2;
    const int BS = 2 * WP + 2 * H;
    int i = blockIdx.x * 256 + threadIdx.x;
    if (i >= n) return;
    const int ch = (i & 7) * 32;
    const int bc = i >> 3;
    const int b  = bc / BS;
    const int e  = bc - b * BS;
    int padpos;
    if (e < WP)            padpos = e;
    else if (e < 2 * WP)   padpos = (H + 1) * WP + (e - WP);
    else {
        const int e2 = e - 2 * WP;
        padpos = ((e2 >> 1) + 1) * WP + ((e2 & 1) ? (W + 1) : 0);
    }
    f16* dst = xT + ((size_t)b * HP * WP + padpos) * C_CH + ch;
    const f16x8 z = {};
#pragma unroll
    for (int j = 0; j < 32; j += 8) *(f16x8*)(dst + j) = z;
}

// =================== MFMA f16 conv3x3 + BN + ReLU (fast path) ==============
// R13-proven schedule; R17: occupancy floor 3 -> 4 blocks/CU.
// If emp != nullptr (ent pass), epilogue fuses ehead dot (exT eliminated).
__global__ __launch_bounds__(256, 4)
void conv_mfma_kernel(const f16* __restrict__ xT, const f16* __restrict__ wT,
                      const float* __restrict__ scale,
                      const float* __restrict__ shift,
                      f16* __restrict__ y, int H, int logW, int opad,
                      float* __restrict__ emp, const float* __restrict__ ehw)
{
    const int W  = 1 << logW;
    const int WP = W + 2, HP = H + 2;
    const int HW = H << logW;
    const int tid  = threadIdx.x;
    const int wv   = tid >> 6, lane = tid & 63;

    // --- XCD-chunked bijective swizzle (nwg % 8 == 0 for all levels) ---
    const int nwg = gridDim.x;
    const int bid = blockIdx.x;
    const int wg  = (bid & 7) * (nwg >> 3) + (bid >> 3);
    const int ocBase = (wg & 1) * 128;     // oc-tiles of one pos-tile adjacent
    const int pBase  = (wg >> 1) * 128;
    const int b    = pBase / HW;
    const int rem0 = pBase - b * HW;

    // 2 x (A[128][32] + B[128][32]) f16 = 32 KB
    __shared__ f16 sbuf[16384];

    f32x4 acc[4][4];
#pragma unroll
    for (int i = 0; i < 4; i++)
#pragma unroll
        for (int j = 0; j < 4; j++) acc[i][j] = (f32x4){0.f, 0.f, 0.f, 0.f};

    // --- staging: per wave, 2 calls A + 2 calls B, 1KB each (lane*16B) ---
    const int lr = lane >> 2, ls = lane & 3;
    const int r0 = (wv * 2) * 16 + lr;
    const int r1 = (wv * 2 + 1) * 16 + lr;
    const int c0s = (ls ^ ((r0 >> 1) & 3)) * 8;
    const int c1s = (ls ^ ((r1 >> 1) & 3)) * 8;
    const f16* aSrc0 = wT + (size_t)(ocBase + r0) * KTOT + c0s;
    const f16* aSrc1 = wT + (size_t)(ocBase + r1) * KTOT + c1s;
    const int pp0 = rem0 + r0, pp1 = rem0 + r1;
    const f16* bSrc0 = xT + ((size_t)(b * HP + (pp0 >> logW) + 1) * WP
                             + (pp0 & (W - 1)) + 1) * C_CH + c0s;
    const f16* bSrc1 = xT + ((size_t)(b * HP + (pp1 >> logW) + 1) * WP
                             + (pp1 & (W - 1)) + 1) * C_CH + c1s;

    // --- fragment ds_read offsets (f16 units), swizzled cols ---
    const int rw = (wv & 1) * 64;
    const int cw = (wv >> 1) * 64;
    const int lm = lane & 15, lq = lane >> 4;
    int aOff[4], bOff[4];
#pragma unroll
    for (int mi = 0; mi < 4; mi++) {
        const int R = rw + mi * 16 + lm;
        aOff[mi] = R * 32 + ((lq ^ ((R >> 1) & 3)) << 3);
    }
#pragma unroll
    for (int ni = 0; ni < 4; ni++) {
        const int R = cw + ni * 16 + lm;
        bOff[ni] = 4096 + R * 32 + ((lq ^ ((R >> 1) & 3)) << 3);
    }

    auto STAGE = [&](int kn, int nb) {
        const int tap = kn >> 8;
        const int kh  = tap / 3;
        const int kw  = tap - 3 * kh;
        const int tOff = ((kh - 1) * WP + (kw - 1)) * C_CH + (kn & 255);
        f16* lb = &sbuf[nb * 8192 + wv * 1024];          // wave-uniform base
        GLL16(aSrc0 + kn, lb);
        GLL16(aSrc1 + kn, lb + 512);
        GLL16(bSrc0 + tOff, lb + 4096);
        GLL16(bSrc1 + tOff, lb + 4096 + 512);
    };

    STAGE(0, 0);
    __syncthreads();                       // drains vmcnt(0) before s_barrier
    int cur = 0;
    for (int k0 = 0; k0 < KTOT; k0 += 32) {
        if (k0 + 32 < KTOT) STAGE(k0 + 32, cur ^ 1);   // overlap with compute
        const f16* sb = &sbuf[cur * 8192];
        f16x8 af[4], bf[4];
#pragma unroll
        for (int mi = 0; mi < 4; mi++) af[mi] = *(const f16x8*)(sb + aOff[mi]);
#pragma unroll
        for (int ni = 0; ni < 4; ni++) bf[ni] = *(const f16x8*)(sb + bOff[ni]);
#pragma unroll
        for (int mi = 0; mi < 4; mi++)
#pragma unroll
            for (int ni = 0; ni < 4; ni++)
                acc[mi][ni] = __builtin_amdgcn_mfma_f32_16x16x32_f16(
                    af[mi], bf[ni], acc[mi][ni], 0, 0, 0);
        __syncthreads();                   // drain next-tile loads + flip
        cur ^= 1;
    }

    float sc[4][4], sh[4][4];
#pragma unroll
    for (int mi = 0; mi < 4; mi++)
#pragma unroll
        for (int r = 0; r < 4; r++) {
            const int oc = ocBase + rw + mi * 16 + lq * 4 + r;
            sc[mi][r] = scale[oc];
            sh[mi][r] = shift[oc];
        }

    if (emp) {
        // fused ehead: per-thread partial dot over 16 ocs x 4 positions,
        // LDS-reduce 8 contributors per position (exact_full<ent> pattern).
        float pni[4] = {0.f, 0.f, 0.f, 0.f};
#pragma unroll
        for (int mi = 0; mi < 4; mi++)
#pragma unroll
            for (int r = 0; r < 4; r++) {
                const float w = ehw[ocBase + rw + mi * 16 + lq * 4 + r];
#pragma unroll
                for (int ni = 0; ni < 4; ni++) {
                    const float v = fmaxf(
                        fmaf(acc[mi][ni][r], sc[mi][r], sh[mi][r]), 0.f);
                    pni[ni] = fmaf(w, v, pni[ni]);
                }
            }
        float* pa = (float*)sbuf;          // [128][8] floats = 4KB
        const int slot = lq + 4 * (wv & 1);
#pragma unroll
        for (int ni = 0; ni < 4; ni++)
            pa[(cw + ni * 16 + lm) * 8 + slot] = pni[ni];
        __syncthreads();
        if (tid < 128) {
            float s = pa[tid * 8];
#pragma unroll
            for (int j = 1; j < 8; j++) s += pa[tid * 8 + j];
            emp[(size_t)(ocBase >> 7) * (4 * (size_t)HW) + pBase + tid] = s;
        }
        return;
    }

#pragma unroll
    for (int ni = 0; ni < 4; ni++) {
        const int pp = rem0 + cw + ni * 16 + lm;
        size_t dst;
        if (opad) {
            const int h2 = pp >> logW, w2 = pp & (W - 1);
            dst = ((size_t)(b * HP + h2 + 1) * WP + (w2 + 1)) * C_CH;
        } else {
            dst = (size_t)(pBase + cw + ni * 16 + lm) * C_CH;
        }
#pragma unroll
        for (int mi = 0; mi < 4; mi++) {
            const int ocb = ocBase + rw + mi * 16 + lq * 4;
            f16x4 o;
#pragma unroll
            for (int r = 0; r < 4; r++)
                o[r] = (f16)fmaxf(fmaf(acc[mi][ni][r], sc[mi][r], sh[mi][r]), 0.f);
            *(f16x4*)(y + dst + ocb) = o;
        }
    }
}

// ========== em finalize: sum 2 oc-tile partials + bias + sigmoid ===========
__global__ __launch_bounds__(256)
void em_fin_kernel(const float* __restrict__ emp, const float* __restrict__ ehb,
                   float* __restrict__ em, int n)
{
    const int i = blockIdx.x * 256 + threadIdx.x;
    if (i >= n) return;
    const float s = emp[i] + emp[(size_t)n + i] + ehb[0];
    em[i] = 1.0f / (1.0f + expf(-s));
}

// ========== em lvl2 = ape lvl2 slice (same dense grid, exact values) =======
__global__ __launch_bounds__(256)
void em2_copy_kernel(const float* __restrict__ ape, float* __restrict__ em)
{
    const int i = blockIdx.x * 256 + threadIdx.x;   // grid 16 -> 4096
    em[i] = ape[8192 + i];
}

// ====== EXACT paired-f16 MFMA, FULL-K, 64oc x 64pos, fused epilogues =======
// 1D grid, XCD-chunked; wgs&3 = oc quarter (adjacent -> B L2 reuse x4).
// share: 912 blocks; ent: 768 blocks. Dbuf staging (proven schedule).
// R17: occupancy floor 2 -> 4 blocks/CU.
template<bool IS_SHARE>
__global__ __launch_bounds__(256, 4)
void exact_full_kernel(const f16* __restrict__ xHg, const f16* __restrict__ xLg,
                       const f16* __restrict__ wH, const f16* __restrict__ wL,
                       const float* __restrict__ scale,
                       const float* __restrict__ shift,
                       f16* __restrict__ xOH, f16* __restrict__ xOL,
                       float* __restrict__ apePart, const float* __restrict__ ehw)
{
    constexpr int NTL    = IS_SHARE ? 19 : 16;
    constexpr int IPITCH = IS_SHARE ? 36 : 34;
    constexpr int IPLANE = IS_SHARE ? 1296 : 1156;

    const int tid  = threadIdx.x;
    const int wv   = tid >> 6, lane = tid & 63;

    // --- XCD-chunked bijective swizzle; oc-quarters adjacent ---
    const int nwg = gridDim.x;             // 912 or 768, % 8 == 0
    const int bid = blockIdx.x;
    const int wgs = (bid & 7) * (nwg >> 3) + (bid >> 3);
    const int ocq = wgs & 3;
    const int ti  = wgs >> 2;
    const int lvlb = ti / NTL;
    const int tile = ti - lvlb * NTL;
    const int posBase = tile * 64;
    const int ocBase  = ocq * 64;
    const int lvl  = lvlb >> 2;

    // 2 x (AsH|AsL|BsH|BsL each [64][32]) = 32 KB; epilogue reuses region
    __shared__ f16 sbuf[16384];

    f32x4 accH[2][2], accX[2][2];
#pragma unroll
    for (int i = 0; i < 2; i++)
#pragma unroll
        for (int j = 0; j < 2; j++) {
            accH[i][j] = (f32x4){0.f, 0.f, 0.f, 0.f};
            accX[i][j] = (f32x4){0.f, 0.f, 0.f, 0.f};
        }

    // --- staging: per wave 4 GLL16 (A-H, A-L, B-H, B-L), rows wv*16..+15 ---
    const int lr = lane >> 2, ls = lane & 3;
    const int rA = wv * 16 + lr;                   // 0..63
    const int cAs = (ls ^ ((rA >> 1) & 3)) * 8;    // pre-swizzled col
    const f16* aSrcH = wH + (size_t)(ocBase + rA) * KTOT + cAs;
    const f16* aSrcL = wL + (size_t)(ocBase + rA) * KTOT + cAs;

    int n = posBase + rA;
    if (IS_SHARE && n > 1155) n = 1155;            // tail tile clamp (masked)
    int po;
    if (IS_SHARE) { const int ph = n / 34; po = ph * 36 + (n - ph * 34); }
    else          { po = (n >> 5) * 34 + (n & 31); }
    const f16* bSrcH = xHg + ((size_t)lvlb * IPLANE + po) * 256 + cAs;
    const f16* bSrcL = xLg + ((size_t)lvlb * IPLANE + po) * 256 + cAs;

    // --- fragment ds_read offsets (f16 units), swizzled cols ---
    const int rw = (wv & 1) * 32;                  // oc within 64
    const int cw = (wv >> 1) * 32;                 // pos within 64
    const int lm = lane & 15, lq = lane >> 4;
    int aOff[2], bOff[2];
#pragma unroll
    for (int mi = 0; mi < 2; mi++) {
        const int R = rw + mi * 16 + lm;
        aOff[mi] = R * 32 + ((lq ^ ((R >> 1) & 3)) << 3);
    }
#pragma unroll
    for (int ni = 0; ni < 2; ni++) {
        const int R = cw + ni * 16 + lm;
        bOff[ni] = R * 32 + ((lq ^ ((R >> 1) & 3)) << 3);
    }

    auto STAGE = [&](int kn, int nb) {
        const int tap = kn >> 8;
        const int th  = tap / 3;
        const int tOff = (th * IPITCH + (tap - 3 * th)) * 256 + (kn & 255);
        f16* lb = &sbuf[nb * 8192 + wv * 512];     // wave-uniform bases
        GLL16(aSrcH + kn, lb);
        GLL16(aSrcL + kn, lb + 2048);
        GLL16(bSrcH + tOff, lb + 4096);
        GLL16(bSrcL + tOff, lb + 6144);
    };

    STAGE(0, 0);
    __syncthreads();                       // drains vmcnt(0): tile 0 landed
    int cur = 0;
    for (int ko = 0; ko < KTOT; ko += 32) {
        if (ko + 32 < KTOT) STAGE(ko + 32, cur ^ 1);   // overlap with compute
        const f16* sb = &sbuf[cur * 8192];
        f16x8 aH[2], aL[2];
#pragma unroll
        for (int mi = 0; mi < 2; mi++) {
            aH[mi] = *(const f16x8*)(sb + aOff[mi]);
            aL[mi] = *(const f16x8*)(sb + 2048 + aOff[mi]);
        }
#pragma unroll
        for (int ni = 0; ni < 2; ni++) {
            const f16x8 bh = *(const f16x8*)(sb + 4096 + bOff[ni]);
            const f16x8 bl = *(const f16x8*)(sb + 6144 + bOff[ni]);
#pragma unroll
            for (int mi = 0; mi < 2; mi++)
                accH[mi][ni] = __builtin_amdgcn_mfma_f32_16x16x32_f16(
                    aH[mi], bh, accH[mi][ni], 0, 0, 0);
#pragma unroll
            for (int mi = 0; mi < 2; mi++)
                accX[mi][ni] = __builtin_amdgcn_mfma_f32_16x16x32_f16(
                    aH[mi], bl, accX[mi][ni], 0, 0, 0);
#pragma unroll
            for (int mi = 0; mi < 2; mi++)
                accX[mi][ni] = __builtin_amdgcn_mfma_f32_16x16x32_f16(
                    aL[mi], bh, accX[mi][ni], 0, 0, 0);
        }
        __syncthreads();                   // drain next-tile loads + flip
        cur ^= 1;
    }

    if constexpr (IS_SHARE) {
        // BN+ReLU+mask; stage hi/lo into LDS transpose buf, stride 72 f16.
#pragma unroll
        for (int mi = 0; mi < 2; mi++)
#pragma unroll
            for (int r = 0; r < 4; r++) {
                const int chl = rw + mi * 16 + lq * 4 + r;    // 0..63
                const int oc  = ocBase + chl;
                const float sc = scale[lvl * 256 + oc];
                const float sh = shift[lvl * 256 + oc];
#pragma unroll
                for (int ni = 0; ni < 2; ni++) {
                    const int pl  = cw + ni * 16 + lm;        // 0..63
                    const int nn  = posBase + pl;
                    const float val = accH[mi][ni][r]
                                    + accX[mi][ni][r] * (1.0f / 1024.0f);
                    const int ph = nn / 34;
                    const int pw = nn - ph * 34;
                    const bool valid = (nn < 1156) && (ph >= 1) && (pw >= 1) &&
                                       (lvl < 2 || (ph <= 32 && pw <= 32));
                    const float o = valid ? fmaxf(fmaf(val, sc, sh), 0.f) : 0.f;
                    const f16 h = (f16)o;
                    sbuf[pl * 72 + chl]        = h;
                    sbuf[4608 + pl * 72 + chl] = (f16)((o - (float)h) * 1024.f);
                }
            }
        __syncthreads();
        const int p  = tid >> 2;
        const int cg = (tid & 3) * 16;
        const int n2 = posBase + p;
        if (n2 < 1156) {
            const size_t gb = ((size_t)lvlb * 1156 + n2) * 256 + ocBase + cg;
            *(f16x8*)(xOH + gb)     = *(const f16x8*)(sbuf + p * 72 + cg);
            *(f16x8*)(xOH + gb + 8) = *(const f16x8*)(sbuf + p * 72 + cg + 8);
            *(f16x8*)(xOL + gb)     = *(const f16x8*)(sbuf + 4608 + p * 72 + cg);
            *(f16x8*)(xOL + gb + 8) = *(const f16x8*)(sbuf + 4608 + p * 72 + cg + 8);
        }
    } else {
        // BN+ReLU; ehead contraction over this block's 64-oc slice
        float* pa = (float*)sbuf;          // [64 cells][8 contributors]
        float pni[2] = {0.f, 0.f};
#pragma unroll
        for (int mi = 0; mi < 2; mi++)
#pragma unroll
            for (int r = 0; r < 4; r++) {
                const int oc = ocBase + rw + mi * 16 + lq * 4 + r;
                const float sc = scale[768 + lvl * 256 + oc];
                const float sh = shift[768 + lvl * 256 + oc];
                const float w  = ehw[oc];
#pragma unroll
                for (int ni = 0; ni < 2; ni++) {
                    const float val = accH[mi][ni][r]
                                    + accX[mi][ni][r] * (1.0f / 1024.0f);
                    pni[ni] = fmaf(w, fmaxf(fmaf(val, sc, sh), 0.f), pni[ni]);
                }
            }
        const int slot = lq + 4 * (wv & 1);
#pragma unroll
        for (int ni = 0; ni < 2; ni++)
            pa[(cw + ni * 16 + lm) * 8 + slot] = pni[ni];
        __syncthreads();
        if (tid < 64) {
            float s = pa[tid * 8];
#pragma unroll
            for (int j = 1; j < 8; j++) s += pa[tid * 8 + j];
            apePart[(size_t)ocq * 12288 + lvlb * 1024 + posBase + tid] = s;
        }
    }
}

// ======= ape finalize: sum 4 oc-quarter partials + bias + sigmoid ==========
__global__ __launch_bounds__(256)
void ape_fin_kernel(const float* __restrict__ apePart,
                    const float* __restrict__ ehb, float* __restrict__ ape)
{
    const int i = blockIdx.x * 256 + threadIdx.x;
    if (i >= 12288) return;
    float s = apePart[i];
    s += apePart[12288 + i];
    s += apePart[24576 + i];
    s += apePart[36864 + i];
    ape[i] = 1.0f / (1.0f + expf(-(s + ehb[0])));
}

// ===================== top-k, all levels (grid 12) =========================
__global__ __launch_bounds__(1024)
void topk_all_kernel(const float* __restrict__ ape, const int* __restrict__ coords,
                     int* __restrict__ xy_int, float* __restrict__ out,
                     int xo0, int xo1, int xo2)
{
    const int lvl = blockIdx.x >> 2;
    const int b   = blockIdx.x & 3;
    const int nk  = 512 >> lvl;
    const int tid = threadIdx.x;
    __shared__ unsigned long long keys[1024];

    const int rr = coords[tid] & 31;
    const int cc0 = coords[1024 + tid] & 31;
    const float v = ape[lvl * 4096 + (b << 10) + (rr << 5) + cc0];
    unsigned u = __float_as_uint(v);
    unsigned mono = (u & 0x80000000u) ? ~u : (u | 0x80000000u);
    keys[tid] = (((unsigned long long)(~mono)) << 32) | (unsigned)tid;
    __syncthreads();

    for (int k = 2; k <= 1024; k <<= 1) {
        for (int j = k >> 1; j > 0; j >>= 1) {
            const int ixj = tid ^ j;
            if (ixj > tid) {
                const bool up = ((tid & k) == 0);
                const unsigned long long a = keys[tid], c = keys[ixj];
                if ((a > c) == up) { keys[tid] = c; keys[ixj] = a; }
            }
            __syncthreads();
        }
    }

    if (tid < nk) {
        const int i  = (int)(keys[tid] & 0x3FFu);
        const int r  = coords[i] & 31;
        const int c  = coords[1024 + i] & 31;
        const int intOff = 8192 - (8192 >> lvl);
        const int o  = intOff + (b * nk + tid) * 2;
        xy_int[o]     = r;
        xy_int[o + 1] = c;
        const int xo = (lvl == 0) ? xo0 : (lvl == 1 ? xo1 : xo2);
        out[xo + (b * nk + tid) * 2]     = (float)r;
        out[xo + (b * nk + tid) * 2 + 1] = (float)c;
    }
}

// ====== pat conv at top-k: paired-f16 MFMA, 32pos x 64oc, split-K x2 =======
// R17: occupancy floor 2 -> 4 blocks/CU (LDS 24KB).
__global__ __launch_bounds__(256, 4)
void pat_mfma_kernel(const f16* __restrict__ xHg, const f16* __restrict__ xLg,
                     const f16* __restrict__ wH, const f16* __restrict__ wL,
                     const int* __restrict__ xy_int,
                     float* __restrict__ part)
{
    const int tid = threadIdx.x;
    const int wv  = tid >> 6, lane = tid & 63;
    const int nwg = gridDim.x;             // 896
    const int bid = blockIdx.x;
    const int wgs = (bid & 7) * (nwg >> 3) + (bid >> 3);
    const int z   = wgs & 1;
    const int ocq = (wgs >> 1) & 3;
    const int ti  = wgs >> 3;              // 0..111
    int lvl, pL;
    if (ti < 64)      { lvl = 0; pL = ti * 32; }
    else if (ti < 96) { lvl = 1; pL = (ti - 64) * 32; }
    else              { lvl = 2; pL = (ti - 96) * 32; }
    const int nk   = 512 >> lvl;
    const int bb   = pL / nk;
    const int lvlb = lvl * 4 + bb;
    const int intOff   = 8192 - (8192 >> lvl);
    const int posStart = 4096 - (4096 >> lvl);
    const int ocBase = ocq * 64;
    const int kStart = z * 1152;

    // 2 x (AH[64][32] | AL[64][32] | BH[32][32] | BL[32][32]) = 24 KB
    __shared__ f16 sbuf[12288];
    __shared__ int pofs[32];

    if (tid < 32) {
        const int n = pL + tid;
        const int r = xy_int[intOff + n * 2]     & 31;
        const int c = xy_int[intOff + n * 2 + 1] & 31;
        pofs[tid] = r * 34 + c;            // corner of 3x3 window (padded)
    }
    __syncthreads();

    f32x4 accH[2], accX[2];
#pragma unroll
    for (int i = 0; i < 2; i++) {
        accH[i] = (f32x4){0.f, 0.f, 0.f, 0.f};
        accX[i] = (f32x4){0.f, 0.f, 0.f, 0.f};
    }

    const int lr = lane >> 2, ls = lane & 3;
    // A: wave wv stages oc rows wv*16..+15 (hi and lo)
    const int rA  = wv * 16 + lr;
    const int cAs = (ls ^ ((rA >> 1) & 3)) * 8;
    const f16* aSrcH = wH + (size_t)(ocBase + rA) * KTOT + kStart + cAs;
    const f16* aSrcL = wL + (size_t)(ocBase + rA) * KTOT + kStart + cAs;
    // B: waves 0,1 stage B-H rows 0-15/16-31; waves 2,3 stage B-L same rows
    const int rB  = (wv & 1) * 16 + lr;    // 0..31
    const int cBs = (ls ^ ((rB >> 1) & 3)) * 8;
    const f16* bBase = (wv < 2) ? xHg : xLg;
    const f16* bSrc = bBase + ((size_t)lvlb * 1156 + pofs[rB]) * 256 + cBs;
    const int bDst = ((wv < 2) ? 4096 : 5120) + (wv & 1) * 512;

    // frag offsets
    const int rw = (wv & 1) * 32;          // oc within 64
    const int pw = (wv >> 1) * 16;         // pos within 32
    const int lm = lane & 15, lq = lane >> 4;
    int aOff[2];
#pragma unroll
    for (int mi = 0; mi < 2; mi++) {
        const int R = rw + mi * 16 + lm;
        aOff[mi] = R * 32 + ((lq ^ ((R >> 1) & 3)) << 3);
    }
    const int Rb = pw + lm;
    const int bOff = 4096 + Rb * 32 + ((lq ^ ((Rb >> 1) & 3)) << 3);

    auto STAGE = [&](int kRel, int nb) {
        const int kAbs = kStart + kRel;
        const int tap  = kAbs >> 8;
        const int th   = tap / 3;
        const int tOff = (th * 34 + (tap - 3 * th)) * 256 + (kAbs & 255);
        f16* base = &sbuf[nb * 6144];
        GLL16(aSrcH + kRel, base + wv * 512);            // A-H
        GLL16(aSrcL + kRel, base + 2048 + wv * 512);     // A-L
        GLL16(bSrc + tOff,  base + bDst);                // B (H or L half)
    };

    STAGE(0, 0);
    __syncthreads();                       // drains vmcnt(0): tile 0 landed
    int cur = 0;
    for (int ko = 0; ko < 1152; ko += 32) {
        if (ko + 32 < 1152) STAGE(ko + 32, cur ^ 1);   // overlap with compute
        const f16* sb = &sbuf[cur * 6144];
        f16x8 aH[2], aL[2];
#pragma unroll
        for (int mi = 0; mi < 2; mi++) {
            aH[mi] = *(const f16x8*)(sb + aOff[mi]);
            aL[mi] = *(const f16x8*)(sb + 2048 + aOff[mi]);
        }
        const f16x8 bh = *(const f16x8*)(sb + bOff);
        const f16x8 bl = *(const f16x8*)(sb + 1024 + bOff);
#pragma unroll
        for (int mi = 0; mi < 2; mi++)
            accH[mi] = __builtin_amdgcn_mfma_f32_16x16x32_f16(
                aH[mi], bh, accH[mi], 0, 0, 0);
#pragma unroll
        for (int mi = 0; mi < 2; mi++)
            accX[mi] = __builtin_amdgcn_mfma_f32_16x16x32_f16(
                aH[mi], bl, accX[mi], 0, 0, 0);
#pragma unroll
        for (int mi = 0; mi < 2; mi++)
            accX[mi] = __builtin_amdgcn_mfma_f32_16x16x32_f16(
                aL[mi], bh, accX[mi], 0, 0, 0);
        __syncthreads();                   // drain next-tile loads + flip
        cur ^= 1;
    }

    // raw conv partials, [pos][256] fp32; BN applied in pat_reduce
    float* op = part + (size_t)z * PAT_N
              + (size_t)(posStart + pL + pw + lm) * C_CH + ocBase;
#pragma unroll
    for (int mi = 0; mi < 2; mi++)
#pragma unroll
        for (int r = 0; r < 4; r++)
            op[rw + mi * 16 + lq * 4 + r] =
                accH[mi][r] + accX[mi][r] * (1.0f / 1024.0f);
}

// ===== pat split-K x2 reduce (fixed order) + BN + ReLU -> af [3584][256] ===
__global__ __launch_bounds__(256)
void pat_reduce_kernel(const float* __restrict__ part,
                       const float* __restrict__ cb,
                       const float* __restrict__ bng, const float* __restrict__ bnb,
                       const float* __restrict__ bnm, const float* __restrict__ bnv,
                       float* __restrict__ af)
{
    const int i4 = (blockIdx.x * 256 + threadIdx.x) * 4;
    if (i4 >= PAT_N) return;
    const int pos = i4 >> 8;
    const int oc0 = i4 & 255;
    const int lvl = (pos < 2048) ? 0 : (pos < 3072 ? 1 : 2);
    float4 s = *(const float4*)(part + i4);
    {
        const float4 t = *(const float4*)(part + (size_t)PAT_N + i4);
        s.x += t.x; s.y += t.y; s.z += t.z; s.w += t.w;
    }
    const float4 g  = *(const float4*)(bng + lvl * 256 + oc0);
    const float4 bb = *(const float4*)(bnb + lvl * 256 + oc0);
    const float4 m  = *(const float4*)(bnm + lvl * 256 + oc0);
    const float4 v  = *(const float4*)(bnv + lvl * 256 + oc0);
    const float4 cb4 = *(const float4*)(cb + oc0);
    float4 o;
    {
        float inv = 1.0f / sqrtf(v.x + 1e-5f); float sc = g.x * inv;
        o.x = fmaxf(fmaf(s.x, sc, (cb4.x - m.x) * sc + bb.x), 0.f);
        inv = 1.0f / sqrtf(v.y + 1e-5f); sc = g.y * inv;
        o.y = fmaxf(fmaf(s.y, sc, (cb4.y - m.y) * sc + bb.y), 0.f);
        inv = 1.0f / sqrtf(v.z + 1e-5f); sc = g.z * inv;
        o.z = fmaxf(fmaf(s.z, sc, (cb4.z - m.z) * sc + bb.z), 0.f);
        inv = 1.0f / sqrtf(v.w + 1e-5f); sc = g.w * inv;
        o.w = fmaxf(fmaf(s.w, sc, (cb4.w - m.w) * sc + bb.w), 0.f);
    }
    *(float4*)(af + i4) = o;
}

// ============ head + final boxes, all levels (grid 3584) ===================
__global__ __launch_bounds__(256)
void head_final_all_kernel(const float* __restrict__ af, const float* __restrict__ hw,
                           const float* __restrict__ hb, const int* __restrict__ xy_int,
                           float* __restrict__ out, int fo0, int fo1, int fo2)
{
    const int pos = blockIdx.x;
    const int lvl = (pos < 2048) ? 0 : (pos < 3072 ? 1 : 2);
    const int local = pos - (4096 - (4096 >> lvl));
    const int intOff = 8192 - (8192 >> lvl);
    const int fo = (lvl == 0) ? fo0 : (lvl == 1 ? fo1 : fo2);
    const int tid  = threadIdx.x;
    const int j4   = tid >> 6;
    const int lane = tid & 63;
    const float* a = af + (size_t)pos * C_CH;
    const float* w = hw + j4 * C_CH;
    float sum = 0.f;
#pragma unroll
    for (int i = 0; i < 4; i++)
        sum = fmaf(a[lane + 64 * i], w[lane + 64 * i], sum);
#pragma unroll
    for (int off = 32; off > 0; off >>= 1) sum += __shfl_down(sum, off);
    if (lane == 0) {
        const float pc = 1.0f / (1.0f + expf(-(sum + hb[j4])));
        const float ax = (float)xy_int[intOff + local * 2];
        const float ay = (float)xy_int[intOff + local * 2 + 1];
        float val;
        if      (j4 == 0) val = ax - 16.0f * pc;
        else if (j4 == 1) val = ay - 16.0f * pc;
        else if (j4 == 2) val = ax + 16.0f * pc;
        else              val = ay + 16.0f * pc;
        out[fo + local * 4 + j4] = val;
    }
}

// ============================== launcher ===================================
extern "C" void kernel_launch(void* const* d_in, const int* in_sizes, int n_in,
                              void* d_out, int out_size, void* d_ws, size_t ws_size,
                              hipStream_t stream) {
    const float* feat[3] = {(const float*)d_in[0], (const float*)d_in[1],
                            (const float*)d_in[2]};
    const int*   coords  = (const int*)d_in[3];
    const float* sw  = (const float*)d_in[4];
    const float* sb  = (const float*)d_in[5];
    const float* sg  = (const float*)d_in[6];
    const float* sbb = (const float*)d_in[7];
    const float* smm = (const float*)d_in[8];
    const float* svv = (const float*)d_in[9];
    const float* ew  = (const float*)d_in[10];
    const float* eb  = (const float*)d_in[11];
    const float* eg  = (const float*)d_in[12];
    const float* ebb = (const float*)d_in[13];
    const float* emm = (const float*)d_in[14];
    const float* evv = (const float*)d_in[15];
    const float* pw  = (const float*)d_in[16];
    const float* pb  = (const float*)d_in[17];
    const float* pg  = (const float*)d_in[18];
    const float* pbb = (const float*)d_in[19];
    const float* pmm = (const float*)d_in[20];
    const float* pvv = (const float*)d_in[21];
    const float* ehw = (const float*)d_in[22];
    const float* ehb = (const float*)d_in[23];
    const float* hww = (const float*)d_in[24];
    const float* hbb = (const float*)d_in[25];

    float* out = (float*)d_out;
    char*  ws  = (char*)d_ws;

    // ---- workspace layout (bytes from ws) ----
    f16*   wTs    = (f16*)(ws);                         // 0        (1.18MB)
    f16*   wTe    = (f16*)(ws + 1310720);
    f16*   wTsL   = (f16*)(ws + 2621440);
    f16*   wTeL   = (f16*)(ws + 3932160);
    float* scales = (float*)(ws + 5242880);
    float* shifts = (float*)(ws + 5251072);
    // exact path
    f16*   fpadH  = (f16*)(ws + 6291456);               // 6MB   (7.96MB)
    f16*   fpadL  = (f16*)(ws + 14254080);              // contiguous after H
    float* patPart= (float*)(ws + 6291456);             // reuses fpad16 (dead)
    float* emPart = (float*)(ws + 6291456);             // fast path: dead region
    float* af     = (float*)(ws + 23068672);            // 22MB  (3.5MB)
    f16*   wTp    = (f16*)(ws + 27262976);              // exact-path-only; the
    f16*   wTpL   = (f16*)(ws + 28573696);              // fast path clobbers
    f16*   xspH   = (f16*)(ws + 90177536);              // 86MB  (6.8MB)
    f16*   xspL   = (f16*)(ws + 97280000);
    float* ape    = (float*)(ws + 119537664);           // 114MB (48KB)
    int*   xy_int = (int*)  (ws + 119603200);           // (32KB)
    float* apePart= (float*)(ws + 119668736);           // (192KB)
    // fast path (runs after exact path; reuses dead exact regions)
    f16*   featT  = (f16*)(ws + 27262976);              // 26MB (34.6MB, lvl0)
    f16*   xsT    = (f16*)(ws + 65011712);              // 62MB (34.6MB) disjoint

    const int Hs[3]    = {128, 64, 32};
    const int logWs[3] = {7, 6, 5};
    const int nks[3]   = {512, 256, 128};

    size_t off = 0;
    size_t emOff[3], finOff[3], xyOff[3];
    for (int l = 0; l < 3; l++) {
        const int HW = Hs[l] * Hs[l];
        emOff[l]  = off; off += (size_t)4 * HW;
        finOff[l] = off; off += (size_t)4 * nks[l] * 4;
        xyOff[l]  = off; off += (size_t)4 * nks[l] * 2;
    }

    // -------- prep --------
    prep_weights_kernel<<<(C_CH * KTOT + 255) / 256, 256, 0, stream>>>(
        sw, ew, pw, wTs, wTe, wTsL, wTeL, wTp, wTpL, C_CH * KTOT);
    prep_bn_kernel<<<6, 256, 0, stream>>>(sg, sbb, smm, svv, sb,
                                          eg, ebb, emm, evv, eb, scales, shifts);

    // -------- exact path --------
    zero16_kernel<<<(995328 + 255) / 256, 256, 0, stream>>>((f16x8*)fpadH, 995328);
    fpad16_fill_kernel<<<dim3(34, 12), 256, 0, stream>>>(
        feat[0], feat[1], feat[2], fpadH, fpadL);
    exact_full_kernel<true><<<912, 256, 0, stream>>>(
        fpadH, fpadL, wTs, wTsL, scales, shifts, xspH, xspL,
        nullptr, nullptr);
    exact_full_kernel<false><<<768, 256, 0, stream>>>(
        xspH, xspL, wTe, wTeL, scales, shifts, nullptr, nullptr,
        apePart, ehw);
    ape_fin_kernel<<<48, 256, 0, stream>>>(apePart, ehb, ape);
    topk_all_kernel<<<12, 1024, 0, stream>>>(
        ape, coords, xy_int, out, (int)xyOff[0], (int)xyOff[1], (int)xyOff[2]);
    pat_mfma_kernel<<<896, 256, 0, stream>>>(
        xspH, xspL, wTp, wTpL, xy_int, patPart);
    pat_reduce_kernel<<<(PAT_N / 1024), 256, 0, stream>>>(
        patPart, pb, pg, pbb, pmm, pvv, af);
    head_final_all_kernel<<<PAT_POS, 256, 0, stream>>>(
        af, hww, hbb, xy_int, out, (int)finOff[0], (int)finOff[1], (int)finOff[2]);

    // -------- fast path (f16 MFMA), lvl 0..1 only --------
    // (lvl2 em == ape lvl2 slice exactly: same dense grid, exact math.)
    for (int lvl = 0; lvl < 2; lvl++) {
        const int H = Hs[lvl], logW = logWs[lvl];
        const int W = H;
        const int HW = H << logW;
        const int WP = W + 2;
        const int nbord = 4 * (2 * WP + 2 * H) * 8;

        pad_hwc_kernel<<<4 * HW / 64, 256, 0, stream>>>(feat[lvl], featT, H, logW);
        zero_cl_border_kernel<<<(nbord + 255) / 256, 256, 0, stream>>>(
            featT, H, W, nbord);
        zero_cl_border_kernel<<<(nbord + 255) / 256, 256, 0, stream>>>(
            xsT, H, W, nbord);
        dim3 gconv((4 * HW / 128) * 2);     // 1D: wg&1 = oc tile, wg>>1 = pos
        conv_mfma_kernel<<<gconv, 256, 0, stream>>>(
            featT, wTs, scales + lvl * 256, shifts + lvl * 256, xsT, H, logW, 1,
            nullptr, nullptr);
        conv_mfma_kernel<<<gconv, 256, 0, stream>>>(
            xsT, wTe, scales + 768 + lvl * 256, shifts + 768 + lvl * 256,
            nullptr, H, logW, 0, emPart, ehw);
        em_fin_kernel<<<(4 * HW + 255) / 256, 256, 0, stream>>>(
            emPart, ehb, out + emOff[lvl], 4 * HW);
    }
    em2_copy_kernel<<<16, 256, 0, stream>>>(ape, out + emOff[2]);
}